// Round 1
// baseline (421.497 us; speedup 1.0000x reference)
//
#include <hip/hip_runtime.h>
#include <cstdint>
#include <cstddef>

// ---------------------------------------------------------------------------
// Block_85375359910651: RPE-attention transformer block on gfx950.
// B=32 T=500 C=512 H=8 D=64, buckets=49. bf16 MFMA pipeline (threshold 0.106).
//
// rpe[b,h,t,s] == rpe_table[b//4, bucket[8*(b%4)+h, t, s]]  (torch-reshape algebra)
// ---------------------------------------------------------------------------

typedef unsigned short ushort_t;
typedef __bf16 bf16x8 __attribute__((ext_vector_type(8)));
typedef float floatx4 __attribute__((ext_vector_type(4)));
typedef unsigned short ushort4v __attribute__((ext_vector_type(4)));
typedef unsigned short ushort8v __attribute__((ext_vector_type(8)));

#define DEV __device__ __forceinline__

#define B_ 32
#define T_ 500
#define C_ 512
#define H_ 8
#define M_ 16000      // B*T
#define MP_ 16016     // padded rows for qkv buffer (attention tiles read to 512)

// ---- workspace layout (bytes). total 110,940,672 (~111 MB) ----
// qkv region reused by h after attention; x_bf region reused by x1 after LN1.
#define OFF_QKV    0ULL            // 16016*1536*2 = 49,201,152   (later: h 16000*1024*2)
#define OFF_XBF    49201152ULL     // 16,384,000                  (later: x1)
#define OFF_BUCKET 65585152ULL     // 8,000,000   u8 (32,500,500)
#define OFF_VT     73585152ULL     // 16,777,216  bf16 (32,8,64,512)
#define OFF_Y      90362368ULL     // 16,384,000  bf16 attn out
#define OFF_WATTN  106746368ULL    // 1,572,864   bf16 (1536,512) = w_attn^T
#define OFF_WPROJ  108319232ULL    // 524,288     bf16 (512,512)
#define OFF_WFC    108843520ULL    // 1,048,576   bf16 (1024,512)
#define OFF_WFC2   109892096ULL    // 1,048,576   bf16 (512,1024)

DEV ushort_t f2bf(float f) {
  union { float f; unsigned u; } v; v.f = f;
  unsigned r = v.u + 0x7fffu + ((v.u >> 16) & 1u);   // RNE
  return (ushort_t)(r >> 16);
}
DEV float bf2f(ushort_t u) {
  union { unsigned u; float f; } v; v.u = ((unsigned)u) << 16;
  return v.f;
}

// async global->LDS, 16B per lane. lds base must be wave-uniform; HW adds lane*16.
DEV void gload16(const void* g, void* l) {
  __builtin_amdgcn_global_load_lds(
      (__attribute__((address_space(1))) void*)(g),
      (__attribute__((address_space(3))) void*)(l), 16, 0, 0);
}

// ---------------------------------------------------------------------------
// elementwise fp32 -> bf16 (x)
// ---------------------------------------------------------------------------
__global__ __launch_bounds__(256) void cvt_bf16(const float* __restrict__ in,
                                                ushort_t* __restrict__ out, int n) {
  int i = (blockIdx.x * 256 + threadIdx.x) * 4;
  if (i >= n) return;
  float4 v = *(const float4*)(in + i);
  ushort4v o = { f2bf(v.x), f2bf(v.y), f2bf(v.z), f2bf(v.w) };
  *(ushort4v*)(out + i) = o;
}

// ---------------------------------------------------------------------------
// weight (K,N) fp32 -> (N,K) bf16 transposed (one-time; enables B^T GEMM reads)
// grid: (N/32, K/32), 256 threads
// ---------------------------------------------------------------------------
__global__ __launch_bounds__(256) void wtrans_kernel(const float* __restrict__ w,
                                                     ushort_t* __restrict__ wt,
                                                     int K, int N) {
  __shared__ float tile[32][33];
  const int n0 = blockIdx.x * 32, k0 = blockIdx.y * 32;
  const int c = threadIdx.x & 31, r = threadIdx.x >> 5;  // r in [0,8)
#pragma unroll
  for (int rr = 0; rr < 4; ++rr)
    tile[r + rr * 8][c] = w[(size_t)(k0 + r + rr * 8) * N + n0 + c];
  __syncthreads();
#pragma unroll
  for (int rr = 0; rr < 4; ++rr)
    wt[(size_t)(n0 + r + rr * 8) * K + k0 + c] = f2bf(tile[c][r + rr * 8]);
}

// ---------------------------------------------------------------------------
// bucket ids: (32,500,500) u8.  grid (500, 32), 512 threads
// ---------------------------------------------------------------------------
__global__ __launch_bounds__(512) void bucket_kernel(const int* __restrict__ ct,
                                                     unsigned char* __restrict__ bucket) {
  const int t = blockIdx.x, b = blockIdx.y;
  const int s = threadIdx.x;
  if (s >= T_) return;
  const float ax = (float)ct[((size_t)b * T_ + t) * 2];
  const float ay = (float)ct[((size_t)b * T_ + t) * 2 + 1];
  const float bx = (float)ct[((size_t)b * T_ + s) * 2];
  const float by = (float)ct[((size_t)b * T_ + s) * 2 + 1];
  const float dx = ax - bx, dy = ay - by;
  const float dist = sqrtf(dx * dx + dy * dy);      // exact: int sums < 2^24
  const float rel = truncf(dist / 12.0f);
  float idx;
  if (rel <= 12.0f) idx = rel;                      // rel already integral, >=0
  else idx = fminf(rintf(12.0f + logf(rel / 12.0f) / 2.0794415416798357f * 12.0f), 24.0f);
  bucket[((size_t)b * T_ + t) * T_ + s] = (unsigned char)((int)idx + 24);
}

// ---------------------------------------------------------------------------
// GEMM: C(M x N) = A(M x K) * Bt(N x K)^T  with epilogues. m97 structure.
// 128x128 tile, BK=32, 256 threads (2x2 waves of 64x64), 16x16x32 bf16 MFMA.
// EPI 0: bf16(acc+bias)        1: bf16(gelu(acc+bias))
//     2: f32(acc+bias+resf)    3: f32(acc+bias+bf2f(resb))
// ---------------------------------------------------------------------------
template <int EPI>
__global__ __launch_bounds__(256) void gemm_bt(const ushort_t* __restrict__ A,
                                               const ushort_t* __restrict__ Bt,
                                               const float* __restrict__ bias,
                                               const float* __restrict__ resf,
                                               const ushort_t* __restrict__ resb,
                                               void* __restrict__ outp,
                                               int N, int K) {
  __shared__ __align__(16) ushort_t As[128 * 32];
  __shared__ __align__(16) ushort_t Bs[128 * 32];
  const int tid = threadIdx.x;
  const int lane = tid & 63, w = tid >> 6;
  const int wm = w >> 1, wn = w & 1;
  const int quad = lane >> 4, l15 = lane & 15;
  const int m0 = blockIdx.y * 128, n0 = blockIdx.x * 128;

  floatx4 acc[4][4] = {};
  const int Lw = w * 1024 + lane * 16;

  for (int k0 = 0; k0 < K; k0 += 32) {
    __syncthreads();
#pragma unroll
    for (int j = 0; j < 2; ++j) {
      const int L = Lw + j * 4096;
      const int row = L >> 6;          // 64B per 32-col bf16 row
      const int kel = (L & 63) >> 1;
      gload16(A + (size_t)(m0 + row) * K + k0 + kel, (char*)As + j * 4096 + w * 1024);
      gload16(Bt + (size_t)(n0 + row) * K + k0 + kel, (char*)Bs + j * 4096 + w * 1024);
    }
    asm volatile("s_waitcnt vmcnt(0)" ::: "memory");
    __syncthreads();

    bf16x8 af[4], bfr[4];
#pragma unroll
    for (int t = 0; t < 4; ++t) {
      af[t]  = *(const bf16x8*)((const char*)As + (wm * 64 + t * 16 + l15) * 64 + quad * 16);
      bfr[t] = *(const bf16x8*)((const char*)Bs + (wn * 64 + t * 16 + l15) * 64 + quad * 16);
    }
#pragma unroll
    for (int tm = 0; tm < 4; ++tm)
#pragma unroll
      for (int tn = 0; tn < 4; ++tn)
        acc[tm][tn] = __builtin_amdgcn_mfma_f32_16x16x32_bf16(af[tm], bfr[tn], acc[tm][tn], 0, 0, 0);
  }

#pragma unroll
  for (int tn = 0; tn < 4; ++tn) {
    const int n = n0 + wn * 64 + tn * 16 + l15;
    const float bs = bias[n];
#pragma unroll
    for (int tm = 0; tm < 4; ++tm) {
#pragma unroll
      for (int r = 0; r < 4; ++r) {
        const int m = m0 + wm * 64 + tm * 16 + quad * 4 + r;
        const float v = acc[tm][tn][r] + bs;
        if (EPI == 0) {
          ((ushort_t*)outp)[(size_t)m * N + n] = f2bf(v);
        } else if (EPI == 1) {
          const float gv = 0.5f * v * (1.0f + erff(v * 0.70710678118654752f));
          ((ushort_t*)outp)[(size_t)m * N + n] = f2bf(gv);
        } else if (EPI == 2) {
          ((float*)outp)[(size_t)m * N + n] = v + resf[(size_t)m * N + n];
        } else {
          ((float*)outp)[(size_t)m * N + n] = v + bf2f(resb[(size_t)m * N + n]);
        }
      }
    }
  }
}

// ---------------------------------------------------------------------------
// V transpose: qkv v-part (b,s,h*64+d) -> vt (b,h,d, s padded to 512), zeros s>=500
// grid (8 s-chunks, 8 h, 32 b), 256 threads
// ---------------------------------------------------------------------------
__global__ __launch_bounds__(256) void vtrans_kernel(const ushort_t* __restrict__ qkv,
                                                     ushort_t* __restrict__ vt) {
  const int sc = blockIdx.x, h = blockIdx.y, b = blockIdx.z;
  __shared__ ushort_t tile[64][65];
  const int tid = threadIdx.x;
#pragma unroll
  for (int j = 0; j < 2; ++j) {
    const int L = j * 4096 + tid * 16;
    const int row = L >> 7, cel = (L & 127) >> 1;
    const ushort_t* src = qkv + (size_t)(b * T_ + sc * 64 + row) * 1536 + 1024 + h * 64 + cel;
    ushort8v val = *(const ushort8v*)src;
#pragma unroll
    for (int e = 0; e < 8; ++e) tile[row][cel + e] = val[e];
  }
  __syncthreads();
#pragma unroll
  for (int j = 0; j < 2; ++j) {
    const int L = j * 4096 + tid * 16;
    const int d = L >> 7, sb = (L & 127) >> 1;
    ushort8v ov;
#pragma unroll
    for (int e = 0; e < 8; ++e) {
      const int s = sc * 64 + sb + e;
      ov[e] = (s < T_) ? tile[sb + e][d] : (ushort_t)0;
    }
    *(ushort8v*)(vt + ((size_t)(b * 8 + h) * 64 + d) * 512 + sc * 64 + sb) = ov;
  }
}

// ---------------------------------------------------------------------------
// fused flash attention with RPE bias.
// grid (4 q-tiles, 8 h, 32 b), 256 threads (4 waves x 32 q-rows).
// ---------------------------------------------------------------------------
__global__ __launch_bounds__(256) void attn_kernel(const ushort_t* __restrict__ qkv,
                                                   const ushort_t* __restrict__ vt,
                                                   const unsigned char* __restrict__ bucket,
                                                   const float* __restrict__ rpe,
                                                   ushort_t* __restrict__ y) {
  const int qt = blockIdx.x, h = blockIdx.y, b = blockIdx.z;
  const int g = b >> 2;               // rpe table row
  const int bpp = 8 * (b & 3) + h;    // bucket batch index

  __shared__ __align__(16) ushort_t Qs[128 * 64];
  __shared__ __align__(16) ushort_t Ks[64 * 64];
  __shared__ __align__(16) ushort_t VTs[64 * 64];
  __shared__ __align__(16) ushort_t Ps[4][32 * 64];
  __shared__ float tbl[52];

  const int tid = threadIdx.x;
  const int lane = tid & 63, w = tid >> 6;
  const int quad = lane >> 4, l15 = lane & 15;
  const int t0 = qt * 128;
  const int q_mrow = w * 32;

  // stage Q tile (128x64 bf16 = 16KB, 4 issues)
#pragma unroll
  for (int j = 0; j < 4; ++j) {
    const int L = j * 4096 + w * 1024 + lane * 16;
    const int row = L >> 7, cel = (L & 127) >> 1;
    gload16(qkv + (size_t)(b * T_ + t0 + row) * 1536 + h * 64 + cel,
            (char*)Qs + j * 4096 + w * 1024);
  }
  if (tid < 49) tbl[tid] = rpe[g * 49 + tid];
  asm volatile("s_waitcnt vmcnt(0)" ::: "memory");
  __syncthreads();

  bf16x8 qf[2][2];
#pragma unroll
  for (int tm = 0; tm < 2; ++tm)
#pragma unroll
    for (int kq = 0; kq < 2; ++kq)
      qf[tm][kq] = *(const bf16x8*)((const char*)Qs + (q_mrow + tm * 16 + l15) * 128 + kq * 64 + quad * 16);

  floatx4 o[2][4] = {};
  float mrow[2][4], lrow[2][4];
#pragma unroll
  for (int tm = 0; tm < 2; ++tm)
#pragma unroll
    for (int r = 0; r < 4; ++r) { mrow[tm][r] = -3.0e38f; lrow[tm][r] = 0.0f; }

  for (int st = 0; st < 8; ++st) {
    const int s0 = st * 64;
    __syncthreads();  // protect K/VT from previous iteration's readers
#pragma unroll
    for (int j = 0; j < 2; ++j) {
      const int L = j * 4096 + w * 1024 + lane * 16;
      const int row = L >> 7, cel = (L & 127) >> 1;
      gload16(qkv + (size_t)(b * T_ + s0 + row) * 1536 + 512 + h * 64 + cel,
              (char*)Ks + j * 4096 + w * 1024);
      gload16(vt + ((size_t)(b * 8 + h) * 64 + row) * 512 + s0 + cel,
              (char*)VTs + j * 4096 + w * 1024);
    }
    asm volatile("s_waitcnt vmcnt(0)" ::: "memory");
    __syncthreads();

    bf16x8 kf[4][2];
#pragma unroll
    for (int tn = 0; tn < 4; ++tn)
#pragma unroll
      for (int kq = 0; kq < 2; ++kq)
        kf[tn][kq] = *(const bf16x8*)((const char*)Ks + (tn * 16 + l15) * 128 + kq * 64 + quad * 16);

    floatx4 sc[2][4];
#pragma unroll
    for (int tm = 0; tm < 2; ++tm)
#pragma unroll
      for (int tn = 0; tn < 4; ++tn) {
        floatx4 z = {0.0f, 0.0f, 0.0f, 0.0f};
        z = __builtin_amdgcn_mfma_f32_16x16x32_bf16(qf[tm][0], kf[tn][0], z, 0, 0, 0);
        sc[tm][tn] = __builtin_amdgcn_mfma_f32_16x16x32_bf16(qf[tm][1], kf[tn][1], z, 0, 0, 0);
      }

    ushort_t* pw = Ps[w];
#pragma unroll
    for (int tm = 0; tm < 2; ++tm) {
#pragma unroll
      for (int r = 0; r < 4; ++r) {
        const int t = t0 + q_mrow + tm * 16 + quad * 4 + r;
        const int tc = (t < T_) ? t : (T_ - 1);
        const size_t brow = ((size_t)bpp * T_ + tc) * (size_t)T_;
        float mx = -3.0e38f;
#pragma unroll
        for (int tn = 0; tn < 4; ++tn) {
          const int s = s0 + tn * 16 + l15;
          float val;
          if (s < T_) {
            val = sc[tm][tn][r] * 0.125f + tbl[bucket[brow + s]];
          } else {
            val = -3.0e30f;
          }
          sc[tm][tn][r] = val;
          mx = fmaxf(mx, val);
        }
        mx = fmaxf(mx, __shfl_xor(mx, 1));
        mx = fmaxf(mx, __shfl_xor(mx, 2));
        mx = fmaxf(mx, __shfl_xor(mx, 4));
        mx = fmaxf(mx, __shfl_xor(mx, 8));
        const float mo = mrow[tm][r];
        const float mn = fmaxf(mo, mx);
        const float al = __expf(mo - mn);
        mrow[tm][r] = mn;
        float rs = 0.0f;
#pragma unroll
        for (int tn = 0; tn < 4; ++tn) {
          const float p = __expf(sc[tm][tn][r] - mn);
          sc[tm][tn][r] = p;
          rs += p;
        }
        rs += __shfl_xor(rs, 1);
        rs += __shfl_xor(rs, 2);
        rs += __shfl_xor(rs, 4);
        rs += __shfl_xor(rs, 8);
        lrow[tm][r] = lrow[tm][r] * al + rs;
#pragma unroll
        for (int nd = 0; nd < 4; ++nd) o[tm][nd][r] *= al;
#pragma unroll
        for (int tn = 0; tn < 4; ++tn)
          pw[(tm * 16 + quad * 4 + r) * 64 + tn * 16 + l15] = f2bf(sc[tm][tn][r]);
      }
    }
    asm volatile("" ::: "memory");  // order P stores before PV frag reads (same wave)

#pragma unroll
    for (int tm = 0; tm < 2; ++tm)
#pragma unroll
      for (int ks = 0; ks < 2; ++ks) {
        const bf16x8 pf = *(const bf16x8*)((const char*)pw + (tm * 16 + l15) * 128 + ks * 64 + quad * 16);
#pragma unroll
        for (int nd = 0; nd < 4; ++nd) {
          const bf16x8 vf = *(const bf16x8*)((const char*)VTs + (nd * 16 + l15) * 128 + ks * 64 + quad * 16);
          o[tm][nd] = __builtin_amdgcn_mfma_f32_16x16x32_bf16(pf, vf, o[tm][nd], 0, 0, 0);
        }
      }
  }

#pragma unroll
  for (int tm = 0; tm < 2; ++tm) {
#pragma unroll
    for (int r = 0; r < 4; ++r) {
      const int t = t0 + q_mrow + tm * 16 + quad * 4 + r;
      if (t < T_) {
        const float inv = 1.0f / lrow[tm][r];
#pragma unroll
        for (int nd = 0; nd < 4; ++nd) {
          const int d = nd * 16 + l15;
          y[((size_t)b * T_ + t) * 512 + h * 64 + d] = f2bf(o[tm][nd][r] * inv);
        }
      }
    }
  }
}

// ---------------------------------------------------------------------------
// LayerNorm over 512 cols. grid 16000 rows, 256 threads (2 elems each).
// out_bf and/or out_f may be null. In-place (z == out_f) is safe: all reads
// complete before the first barrier.
// ---------------------------------------------------------------------------
__global__ __launch_bounds__(256) void ln_kernel(const float* z,
                                                 const float* __restrict__ gw,
                                                 const float* __restrict__ gb,
                                                 ushort_t* out_bf, float* out_f) {
  const int row = blockIdx.x;
  const int tid = threadIdx.x, lane = tid & 63, w = tid >> 6;
  const float* zr = z + (size_t)row * 512;
  const float2 v = *(const float2*)(zr + tid * 2);
  float s = v.x + v.y;
#pragma unroll
  for (int m = 1; m < 64; m <<= 1) s += __shfl_xor(s, m);
  __shared__ float red[8];
  if (lane == 0) red[w] = s;
  __syncthreads();
  const float mean = (red[0] + red[1] + red[2] + red[3]) * (1.0f / 512.0f);
  const float d0 = v.x - mean, d1 = v.y - mean;
  float q = d0 * d0 + d1 * d1;
#pragma unroll
  for (int m = 1; m < 64; m <<= 1) q += __shfl_xor(q, m);
  if (lane == 0) red[4 + w] = q;
  __syncthreads();
  const float var = (red[4] + red[5] + red[6] + red[7]) * (1.0f / 512.0f);
  const float rstd = rsqrtf(var + 1e-5f);
  const int c0 = tid * 2;
  const float o0 = d0 * rstd * gw[c0] + gb[c0];
  const float o1 = d1 * rstd * gw[c0 + 1] + gb[c0 + 1];
  if (out_bf) {
    out_bf[(size_t)row * 512 + c0] = f2bf(o0);
    out_bf[(size_t)row * 512 + c0 + 1] = f2bf(o1);
  }
  if (out_f) {
    float2 ov; ov.x = o0; ov.y = o1;
    *(float2*)(out_f + (size_t)row * 512 + c0) = ov;
  }
}

// ---------------------------------------------------------------------------
extern "C" void kernel_launch(void* const* d_in, const int* in_sizes, int n_in,
                              void* d_out, int out_size, void* d_ws, size_t ws_size,
                              hipStream_t stream) {
  (void)in_sizes; (void)n_in; (void)out_size; (void)ws_size;
  const float* x      = (const float*)d_in[0];
  const int*   ct     = (const int*)d_in[1];
  const float* w_attn = (const float*)d_in[2];
  const float* b_attn = (const float*)d_in[3];
  const float* w_proj = (const float*)d_in[4];
  const float* b_proj = (const float*)d_in[5];
  const float* rpe    = (const float*)d_in[6];
  const float* ln1w   = (const float*)d_in[7];
  const float* ln1b   = (const float*)d_in[8];
  const float* ln2w   = (const float*)d_in[9];
  const float* ln2b   = (const float*)d_in[10];
  const float* w_fc   = (const float*)d_in[11];
  const float* b_fc   = (const float*)d_in[12];
  const float* w_fc2  = (const float*)d_in[13];
  const float* b_fc2  = (const float*)d_in[14];
  float* out = (float*)d_out;

  char* ws = (char*)d_ws;
  ushort_t* qkv     = (ushort_t*)(ws + OFF_QKV);
  ushort_t* h_buf   = (ushort_t*)(ws + OFF_QKV);    // reuse after attention
  ushort_t* x_bf    = (ushort_t*)(ws + OFF_XBF);
  ushort_t* x1      = (ushort_t*)(ws + OFF_XBF);    // reuse after qkv GEMM
  unsigned char* bk = (unsigned char*)(ws + OFF_BUCKET);
  ushort_t* vt      = (ushort_t*)(ws + OFF_VT);
  ushort_t* y       = (ushort_t*)(ws + OFF_Y);
  ushort_t* wt_attn = (ushort_t*)(ws + OFF_WATTN);
  ushort_t* wt_proj = (ushort_t*)(ws + OFF_WPROJ);
  ushort_t* wt_fc   = (ushort_t*)(ws + OFF_WFC);
  ushort_t* wt_fc2  = (ushort_t*)(ws + OFF_WFC2);

  // precompute conversions
  cvt_bf16<<<dim3(8000), 256, 0, stream>>>(x, x_bf, M_ * C_);
  wtrans_kernel<<<dim3(48, 16), 256, 0, stream>>>(w_attn, wt_attn, 512, 1536);
  wtrans_kernel<<<dim3(16, 16), 256, 0, stream>>>(w_proj, wt_proj, 512, 512);
  wtrans_kernel<<<dim3(32, 16), 256, 0, stream>>>(w_fc, wt_fc, 512, 1024);
  wtrans_kernel<<<dim3(16, 32), 256, 0, stream>>>(w_fc2, wt_fc2, 1024, 512);
  bucket_kernel<<<dim3(500, 32), 512, 0, stream>>>(ct, bk);

  // qkv = x @ w_attn + b_attn  (bf16 out)
  gemm_bt<0><<<dim3(12, 125), 256, 0, stream>>>(x_bf, wt_attn, b_attn, nullptr, nullptr, qkv, 1536, 512);
  // v transpose for PV operand layout
  vtrans_kernel<<<dim3(8, 8, 32), 256, 0, stream>>>(qkv, vt);
  // fused flash attention with RPE bias
  attn_kernel<<<dim3(4, 8, 32), 256, 0, stream>>>(qkv, vt, bk, rpe, y);
  // z = x + y @ w_proj + b_proj  (f32, into d_out as scratch)
  gemm_bt<2><<<dim3(4, 125), 256, 0, stream>>>(y, wt_proj, b_proj, x, nullptr, out, 512, 512);
  // x1 = LN1(z) -> bf16
  ln_kernel<<<dim3(16000), 256, 0, stream>>>(out, ln1w, ln1b, x1, nullptr);
  // h = gelu(x1 @ w_fc + b_fc) -> bf16
  gemm_bt<1><<<dim3(8, 125), 256, 0, stream>>>(x1, wt_fc, b_fc, nullptr, nullptr, h_buf, 1024, 512);
  // z2 = x1 + h @ w_fc2 + b_fc2 (f32, into d_out)
  gemm_bt<3><<<dim3(4, 125), 256, 0, stream>>>(h_buf, wt_fc2, b_fc2, nullptr, x1, out, 512, 1024);
  // out = LN2(z2)  (in-place)
  ln_kernel<<<dim3(16000), 256, 0, stream>>>(out, ln2w, ln2b, nullptr, out);
}

// Round 2
// 371.690 us; speedup vs baseline: 1.1340x; 1.1340x over previous
//
#include <hip/hip_runtime.h>
#include <cstdint>
#include <cstddef>

// ---------------------------------------------------------------------------
// Block_85375359910651: RPE-attention transformer block on gfx950.
// B=32 T=500 C=512 H=8 D=64, buckets=49. bf16 MFMA pipeline (threshold 0.106).
// rpe[b,h,t,s] == rpe_table[b//4, bucket[8*(b%4)+h, t, s]]
// R2: no-max softmax, xor-swizzled LDS tiles (conflict-free ds_read_b128),
//     LDS bucket staging, 64-row q-tiles + XCD swizzle, GEMM BK=64 + TN=64.
// ---------------------------------------------------------------------------

typedef unsigned short ushort_t;
typedef __bf16 bf16x8 __attribute__((ext_vector_type(8)));
typedef float floatx4 __attribute__((ext_vector_type(4)));
typedef unsigned short ushort4v __attribute__((ext_vector_type(4)));
typedef unsigned short ushort8v __attribute__((ext_vector_type(8)));

#define DEV __device__ __forceinline__

#define B_ 32
#define T_ 500
#define C_ 512
#define H_ 8
#define M_ 16000      // B*T

// ---- workspace layout (bytes) ----
#define OFF_QKV    0ULL            // 16016*1536*2 = 49,201,152   (later: h 16000*1024*2)
#define OFF_XBF    49201152ULL     // 16,384,000                  (later: x1)
#define OFF_BUCKET 65585152ULL     // 8,000,000   u8 (32,500,500)
#define OFF_VT     73585152ULL     // 16,777,216  bf16 (32,8,64,512)
#define OFF_Y      90362368ULL     // 16,384,000  bf16 attn out
#define OFF_WATTN  106746368ULL    // 1,572,864   bf16 (1536,512) = w_attn^T
#define OFF_WPROJ  108319232ULL    // 524,288     bf16 (512,512)
#define OFF_WFC    108843520ULL    // 1,048,576   bf16 (1024,512)
#define OFF_WFC2   109892096ULL    // 1,048,576   bf16 (512,1024)

DEV ushort_t f2bf(float f) {
  union { float f; unsigned u; } v; v.f = f;
  unsigned r = v.u + 0x7fffu + ((v.u >> 16) & 1u);   // RNE
  return (ushort_t)(r >> 16);
}
DEV float bf2f(ushort_t u) {
  union { unsigned u; float f; } v; v.u = ((unsigned)u) << 16;
  return v.f;
}

DEV void gload16(const void* g, void* l) {
  __builtin_amdgcn_global_load_lds(
      (__attribute__((address_space(1))) void*)(g),
      (__attribute__((address_space(3))) void*)(l), 16, 0, 0);
}

// ---------------------------------------------------------------------------
__global__ __launch_bounds__(256) void cvt_bf16(const float* __restrict__ in,
                                                ushort_t* __restrict__ out, int n) {
  int i = (blockIdx.x * 256 + threadIdx.x) * 4;
  if (i >= n) return;
  float4 v = *(const float4*)(in + i);
  ushort4v o = { f2bf(v.x), f2bf(v.y), f2bf(v.z), f2bf(v.w) };
  *(ushort4v*)(out + i) = o;
}

// ---------------------------------------------------------------------------
__global__ __launch_bounds__(256) void wtrans_kernel(const float* __restrict__ w,
                                                     ushort_t* __restrict__ wt,
                                                     int K, int N) {
  __shared__ float tile[32][33];
  const int n0 = blockIdx.x * 32, k0 = blockIdx.y * 32;
  const int c = threadIdx.x & 31, r = threadIdx.x >> 5;
#pragma unroll
  for (int rr = 0; rr < 4; ++rr)
    tile[r + rr * 8][c] = w[(size_t)(k0 + r + rr * 8) * N + n0 + c];
  __syncthreads();
#pragma unroll
  for (int rr = 0; rr < 4; ++rr)
    wt[(size_t)(n0 + r + rr * 8) * K + k0 + c] = f2bf(tile[c][r + rr * 8]);
}

// ---------------------------------------------------------------------------
__global__ __launch_bounds__(512) void bucket_kernel(const int* __restrict__ ct,
                                                     unsigned char* __restrict__ bucket) {
  const int t = blockIdx.x, b = blockIdx.y;
  const int s = threadIdx.x;
  if (s >= T_) return;
  const float ax = (float)ct[((size_t)b * T_ + t) * 2];
  const float ay = (float)ct[((size_t)b * T_ + t) * 2 + 1];
  const float bx = (float)ct[((size_t)b * T_ + s) * 2];
  const float by = (float)ct[((size_t)b * T_ + s) * 2 + 1];
  const float dx = ax - bx, dy = ay - by;
  const float dist = sqrtf(dx * dx + dy * dy);
  const float rel = truncf(dist / 12.0f);
  float idx;
  if (rel <= 12.0f) idx = rel;
  else idx = fminf(rintf(12.0f + logf(rel / 12.0f) / 2.0794415416798357f * 12.0f), 24.0f);
  bucket[((size_t)b * T_ + t) * T_ + s] = (unsigned char)((int)idx + 24);
}

// ---------------------------------------------------------------------------
// GEMM: C(M x N) = A(M x K) * Bt(N x K)^T.  128 x TN tile, BK=64, xor-swizzled
// LDS (conflict-free b128 frag reads), 256 threads.
// TN=128: 2x2 waves (4x4 acc). TN=64: 4x1 waves (2x4 acc).
// EPI 0: bf16(acc+bias)  1: bf16(gelu)  2: f32(+resf)  3: f32(+bf2f(resb))
// ---------------------------------------------------------------------------
template <int TN, int EPI>
__global__ __launch_bounds__(256) void gemm_bt(const ushort_t* __restrict__ A,
                                               const ushort_t* __restrict__ Bt,
                                               const float* __restrict__ bias,
                                               const float* __restrict__ resf,
                                               const ushort_t* __restrict__ resb,
                                               void* __restrict__ outp,
                                               int N, int K) {
  constexpr int TMW = (TN == 128) ? 4 : 2;
  __shared__ __align__(16) ushort_t As[128 * 64];
  __shared__ __align__(16) ushort_t Bs[TN * 64];
  const int tid = threadIdx.x;
  const int lane = tid & 63, w = tid >> 6;
  const int wm = (TN == 128) ? (w >> 1) : w;
  const int wn = (TN == 128) ? (w & 1) : 0;
  const int quad = lane >> 4, l15 = lane & 15;
  const int m0 = blockIdx.y * 128, n0 = blockIdx.x * TN;

  floatx4 acc[TMW][4] = {};

  for (int k0 = 0; k0 < K; k0 += 64) {
    __syncthreads();
#pragma unroll
    for (int j = 0; j < 4; ++j) {
      const int chunk = j * 256 + tid;
      const int row = chunk >> 3, pos = chunk & 7, c = pos ^ (row & 7);
      gload16(A + (size_t)(m0 + row) * K + k0 + c * 8, (char*)As + j * 4096 + w * 1024);
    }
#pragma unroll
    for (int j = 0; j < TN / 32; ++j) {
      const int chunk = j * 256 + tid;
      const int row = chunk >> 3, pos = chunk & 7, c = pos ^ (row & 7);
      gload16(Bt + (size_t)(n0 + row) * K + k0 + c * 8, (char*)Bs + j * 4096 + w * 1024);
    }
    asm volatile("s_waitcnt vmcnt(0)" ::: "memory");
    __syncthreads();

#pragma unroll
    for (int kq = 0; kq < 2; ++kq) {
      bf16x8 af[TMW], bfr[4];
#pragma unroll
      for (int t = 0; t < TMW; ++t) {
        const int row = wm * (TMW * 16) + t * 16 + l15;
        const int pos = (kq * 4 + quad) ^ (row & 7);
        af[t] = *(const bf16x8*)((const char*)As + row * 128 + pos * 16);
      }
#pragma unroll
      for (int t = 0; t < 4; ++t) {
        const int row = wn * 64 + t * 16 + l15;
        const int pos = (kq * 4 + quad) ^ (row & 7);
        bfr[t] = *(const bf16x8*)((const char*)Bs + row * 128 + pos * 16);
      }
#pragma unroll
      for (int tm = 0; tm < TMW; ++tm)
#pragma unroll
        for (int tn = 0; tn < 4; ++tn)
          acc[tm][tn] = __builtin_amdgcn_mfma_f32_16x16x32_bf16(af[tm], bfr[tn], acc[tm][tn], 0, 0, 0);
    }
  }

#pragma unroll
  for (int tn = 0; tn < 4; ++tn) {
    const int n = n0 + wn * 64 + tn * 16 + l15;
    const float bs = bias[n];
#pragma unroll
    for (int tm = 0; tm < TMW; ++tm) {
#pragma unroll
      for (int r = 0; r < 4; ++r) {
        const int m = m0 + wm * (TMW * 16) + tm * 16 + quad * 4 + r;
        const float v = acc[tm][tn][r] + bs;
        if (EPI == 0) {
          ((ushort_t*)outp)[(size_t)m * N + n] = f2bf(v);
        } else if (EPI == 1) {
          const float gv = 0.5f * v * (1.0f + erff(v * 0.70710678118654752f));
          ((ushort_t*)outp)[(size_t)m * N + n] = f2bf(gv);
        } else if (EPI == 2) {
          ((float*)outp)[(size_t)m * N + n] = v + resf[(size_t)m * N + n];
        } else {
          ((float*)outp)[(size_t)m * N + n] = v + bf2f(resb[(size_t)m * N + n]);
        }
      }
    }
  }
}

// ---------------------------------------------------------------------------
// V transpose: qkv v-part (b,s,h*64+d) -> vt (b,h,d, s padded to 512)
// ---------------------------------------------------------------------------
__global__ __launch_bounds__(256) void vtrans_kernel(const ushort_t* __restrict__ qkv,
                                                     ushort_t* __restrict__ vt) {
  const int sc = blockIdx.x, h = blockIdx.y, b = blockIdx.z;
  __shared__ ushort_t tile[64][65];
  const int tid = threadIdx.x;
#pragma unroll
  for (int j = 0; j < 2; ++j) {
    const int L = j * 4096 + tid * 16;
    const int row = L >> 7, cel = (L & 127) >> 1;
    const ushort_t* src = qkv + (size_t)(b * T_ + sc * 64 + row) * 1536 + 1024 + h * 64 + cel;
    ushort8v val = *(const ushort8v*)src;
#pragma unroll
    for (int e = 0; e < 8; ++e) tile[row][cel + e] = val[e];
  }
  __syncthreads();
#pragma unroll
  for (int j = 0; j < 2; ++j) {
    const int L = j * 4096 + tid * 16;
    const int d = L >> 7, sb = (L & 127) >> 1;
    ushort8v ov;
#pragma unroll
    for (int e = 0; e < 8; ++e) {
      const int s = sc * 64 + sb + e;
      ov[e] = (s < T_) ? tile[sb + e][d] : (ushort_t)0;
    }
    *(ushort8v*)(vt + ((size_t)(b * 8 + h) * 64 + d) * 512 + sc * 64 + sb) = ov;
  }
}

// ---------------------------------------------------------------------------
// fused flash attention with RPE bias. No-max softmax (scores bounded),
// deferred row-sum, LDS bucket staging, xor-swizzled tiles.
// grid 2048 flat (XCD-swizzled decode), 256 threads (4 waves x 16 q-rows).
// ---------------------------------------------------------------------------
__global__ __launch_bounds__(256) void attn_kernel(const ushort_t* __restrict__ qkv,
                                                   const ushort_t* __restrict__ vt,
                                                   const unsigned char* __restrict__ bucket,
                                                   const float* __restrict__ rpe,
                                                   ushort_t* __restrict__ y) {
  // bid swizzle: all 8 q-tiles of one (b,h) land on the same XCD (bid%8 heuristic)
  const int bid = blockIdx.x;
  const int xcd = bid & 7, sl = bid >> 3;
  const int qt = sl & 7;
  const int pair = xcd * 32 + (sl >> 3);
  const int h = pair >> 5, b = pair & 31;
  const int g = b >> 2;
  const int bpp = 8 * (b & 3) + h;

  __shared__ __align__(16) ushort_t Qs[64 * 64];
  __shared__ __align__(16) ushort_t Ks[64 * 64];
  __shared__ __align__(16) ushort_t VTs[64 * 64];
  __shared__ __align__(16) ushort_t Ps[4][16 * 72];   // +16B row pad
  __shared__ __align__(16) unsigned char bkS[64 * 64];
  __shared__ float tbl[64];

  const int tid = threadIdx.x;
  const int lane = tid & 63, w = tid >> 6;
  const int quad = lane >> 4, l15 = lane & 15;
  const int t0 = qt * 64;

  // stage Q tile (swizzled)
#pragma unroll
  for (int j = 0; j < 2; ++j) {
    const int chunk = j * 256 + tid;
    const int row = chunk >> 3, pos = chunk & 7, c = pos ^ (row & 7);
    gload16(qkv + (size_t)(b * T_ + t0 + row) * 1536 + h * 64 + c * 8,
            (char*)Qs + j * 4096 + w * 1024);
  }
  if (tid < 64) tbl[tid] = (tid < 49) ? rpe[g * 49 + tid] : 0.0f;
  asm volatile("s_waitcnt vmcnt(0)" ::: "memory");
  __syncthreads();

  bf16x8 qf[2];
#pragma unroll
  for (int kq = 0; kq < 2; ++kq) {
    const int row = w * 16 + l15;
    const int pos = (kq * 4 + quad) ^ (row & 7);
    qf[kq] = *(const bf16x8*)((const char*)Qs + row * 128 + pos * 16);
  }

  floatx4 o[4] = {};
  float lsum[4] = {0.0f, 0.0f, 0.0f, 0.0f};
  ushort_t* pw = Ps[w];

  for (int st = 0; st < 8; ++st) {
    const int s0 = st * 64;
    __syncthreads();   // protect K/VT/bk from previous iteration's readers
#pragma unroll
    for (int j = 0; j < 2; ++j) {
      const int chunk = j * 256 + tid;
      const int row = chunk >> 3, pos = chunk & 7, c = pos ^ (row & 7);
      gload16(qkv + (size_t)(b * T_ + s0 + row) * 1536 + 512 + h * 64 + c * 8,
              (char*)Ks + j * 4096 + w * 1024);
      gload16(vt + ((size_t)(b * 8 + h) * 64 + row) * 512 + s0 + c * 8,
              (char*)VTs + j * 4096 + w * 1024);
    }
    {
      const int row = tid >> 2, pos = tid & 3;
      const int tr = t0 + row;
      const int trc = (tr < T_) ? tr : (T_ - 1);
      gload16(bucket + (size_t)bpp * 250000 + (size_t)trc * 500 + s0 + pos * 16,
              (char*)bkS + w * 1024);
    }
    asm volatile("s_waitcnt vmcnt(0)" ::: "memory");
    __syncthreads();

    // QK^T
    floatx4 sc[4];
#pragma unroll
    for (int tn = 0; tn < 4; ++tn) {
      floatx4 z = {0.0f, 0.0f, 0.0f, 0.0f};
#pragma unroll
      for (int kq = 0; kq < 2; ++kq) {
        const int row = tn * 16 + l15;
        const int pos = (kq * 4 + quad) ^ (row & 7);
        const bf16x8 kf = *(const bf16x8*)((const char*)Ks + row * 128 + pos * 16);
        z = __builtin_amdgcn_mfma_f32_16x16x32_bf16(qf[kq], kf, z, 0, 0, 0);
      }
      sc[tn] = z;
    }

    // P = exp(score/8 + rpe)   (no max subtraction: scores bounded)
#pragma unroll
    for (int r = 0; r < 4; ++r) {
      const int rloc = quad * 4 + r;
      const int bkrow = (w * 16 + rloc) * 64;
#pragma unroll
      for (int tn = 0; tn < 4; ++tn) {
        const int scol = s0 + tn * 16 + l15;
        const int idx = bkS[bkrow + tn * 16 + l15] & 63;
        const float val = fmaf(sc[tn][r], 0.125f, tbl[idx]);
        const float p = (scol < T_) ? __expf(val) : 0.0f;
        lsum[r] += p;
        pw[rloc * 72 + tn * 16 + l15] = f2bf(p);
      }
    }
    asm volatile("" ::: "memory");   // order P stores before same-wave frag reads

    // PV
#pragma unroll
    for (int ks = 0; ks < 2; ++ks) {
      const bf16x8 pf = *(const bf16x8*)((const char*)pw + l15 * 144 + ks * 64 + quad * 16);
#pragma unroll
      for (int nd = 0; nd < 4; ++nd) {
        const int row = nd * 16 + l15;
        const int pos = (ks * 4 + quad) ^ (row & 7);
        const bf16x8 vf = *(const bf16x8*)((const char*)VTs + row * 128 + pos * 16);
        o[nd] = __builtin_amdgcn_mfma_f32_16x16x32_bf16(pf, vf, o[nd], 0, 0, 0);
      }
    }
  }

  // deferred row-sum reduce + write
#pragma unroll
  for (int r = 0; r < 4; ++r) {
    float s = lsum[r];
    s += __shfl_xor(s, 1);
    s += __shfl_xor(s, 2);
    s += __shfl_xor(s, 4);
    s += __shfl_xor(s, 8);
    const int t = t0 + w * 16 + quad * 4 + r;
    if (t < T_) {
      const float inv = 1.0f / s;
#pragma unroll
      for (int nd = 0; nd < 4; ++nd)
        y[((size_t)b * T_ + t) * 512 + h * 64 + nd * 16 + l15] = f2bf(o[nd][r] * inv);
    }
  }
}

// ---------------------------------------------------------------------------
__global__ __launch_bounds__(256) void ln_kernel(const float* z,
                                                 const float* __restrict__ gw,
                                                 const float* __restrict__ gb,
                                                 ushort_t* out_bf, float* out_f) {
  const int row = blockIdx.x;
  const int tid = threadIdx.x, lane = tid & 63, w = tid >> 6;
  const float* zr = z + (size_t)row * 512;
  const float2 v = *(const float2*)(zr + tid * 2);
  float s = v.x + v.y;
#pragma unroll
  for (int m = 1; m < 64; m <<= 1) s += __shfl_xor(s, m);
  __shared__ float red[8];
  if (lane == 0) red[w] = s;
  __syncthreads();
  const float mean = (red[0] + red[1] + red[2] + red[3]) * (1.0f / 512.0f);
  const float d0 = v.x - mean, d1 = v.y - mean;
  float q = d0 * d0 + d1 * d1;
#pragma unroll
  for (int m = 1; m < 64; m <<= 1) q += __shfl_xor(q, m);
  if (lane == 0) red[4 + w] = q;
  __syncthreads();
  const float var = (red[4] + red[5] + red[6] + red[7]) * (1.0f / 512.0f);
  const float rstd = rsqrtf(var + 1e-5f);
  const int c0 = tid * 2;
  const float o0 = d0 * rstd * gw[c0] + gb[c0];
  const float o1 = d1 * rstd * gw[c0 + 1] + gb[c0 + 1];
  if (out_bf) {
    out_bf[(size_t)row * 512 + c0] = f2bf(o0);
    out_bf[(size_t)row * 512 + c0 + 1] = f2bf(o1);
  }
  if (out_f) {
    float2 ov; ov.x = o0; ov.y = o1;
    *(float2*)(out_f + (size_t)row * 512 + c0) = ov;
  }
}

// ---------------------------------------------------------------------------
extern "C" void kernel_launch(void* const* d_in, const int* in_sizes, int n_in,
                              void* d_out, int out_size, void* d_ws, size_t ws_size,
                              hipStream_t stream) {
  (void)in_sizes; (void)n_in; (void)out_size; (void)ws_size;
  const float* x      = (const float*)d_in[0];
  const int*   ct     = (const int*)d_in[1];
  const float* w_attn = (const float*)d_in[2];
  const float* b_attn = (const float*)d_in[3];
  const float* w_proj = (const float*)d_in[4];
  const float* b_proj = (const float*)d_in[5];
  const float* rpe    = (const float*)d_in[6];
  const float* ln1w   = (const float*)d_in[7];
  const float* ln1b   = (const float*)d_in[8];
  const float* ln2w   = (const float*)d_in[9];
  const float* ln2b   = (const float*)d_in[10];
  const float* w_fc   = (const float*)d_in[11];
  const float* b_fc   = (const float*)d_in[12];
  const float* w_fc2  = (const float*)d_in[13];
  const float* b_fc2  = (const float*)d_in[14];
  float* out = (float*)d_out;

  char* ws = (char*)d_ws;
  ushort_t* qkv     = (ushort_t*)(ws + OFF_QKV);
  ushort_t* h_buf   = (ushort_t*)(ws + OFF_QKV);
  ushort_t* x_bf    = (ushort_t*)(ws + OFF_XBF);
  ushort_t* x1      = (ushort_t*)(ws + OFF_XBF);
  unsigned char* bk = (unsigned char*)(ws + OFF_BUCKET);
  ushort_t* vt      = (ushort_t*)(ws + OFF_VT);
  ushort_t* y       = (ushort_t*)(ws + OFF_Y);
  ushort_t* wt_attn = (ushort_t*)(ws + OFF_WATTN);
  ushort_t* wt_proj = (ushort_t*)(ws + OFF_WPROJ);
  ushort_t* wt_fc   = (ushort_t*)(ws + OFF_WFC);
  ushort_t* wt_fc2  = (ushort_t*)(ws + OFF_WFC2);

  cvt_bf16<<<dim3(8000), 256, 0, stream>>>(x, x_bf, M_ * C_);
  wtrans_kernel<<<dim3(48, 16), 256, 0, stream>>>(w_attn, wt_attn, 512, 1536);
  wtrans_kernel<<<dim3(16, 16), 256, 0, stream>>>(w_proj, wt_proj, 512, 512);
  wtrans_kernel<<<dim3(32, 16), 256, 0, stream>>>(w_fc, wt_fc, 512, 1024);
  wtrans_kernel<<<dim3(16, 32), 256, 0, stream>>>(w_fc2, wt_fc2, 1024, 512);
  bucket_kernel<<<dim3(500, 32), 512, 0, stream>>>(ct, bk);

  // qkv = x @ w_attn + b_attn
  gemm_bt<128, 0><<<dim3(12, 125), 256, 0, stream>>>(x_bf, wt_attn, b_attn, nullptr, nullptr, qkv, 1536, 512);
  vtrans_kernel<<<dim3(8, 8, 32), 256, 0, stream>>>(qkv, vt);
  attn_kernel<<<dim3(2048), 256, 0, stream>>>(qkv, vt, bk, rpe, y);
  // z = x + y @ w_proj + b_proj  (f32, into d_out)
  gemm_bt<64, 2><<<dim3(8, 125), 256, 0, stream>>>(y, wt_proj, b_proj, x, nullptr, out, 512, 512);
  ln_kernel<<<dim3(16000), 256, 0, stream>>>(out, ln1w, ln1b, x1, nullptr);
  // h = gelu(x1 @ w_fc + b_fc)
  gemm_bt<128, 1><<<dim3(8, 125), 256, 0, stream>>>(x1, wt_fc, b_fc, nullptr, nullptr, h_buf, 1024, 512);
  // z2 = x1 + h @ w_fc2 + b_fc2
  gemm_bt<64, 3><<<dim3(8, 125), 256, 0, stream>>>(h_buf, wt_fc2, b_fc2, nullptr, x1, out, 512, 1024);
  ln_kernel<<<dim3(16000), 256, 0, stream>>>(out, ln2w, ln2b, nullptr, out);
}

// Round 3
// 357.459 us; speedup vs baseline: 1.1791x; 1.0398x over previous
//
#include <hip/hip_runtime.h>
#include <cstdint>
#include <cstddef>

// ---------------------------------------------------------------------------
// Block_85375359910651: RPE-attention transformer block on gfx950.
// B=32 T=500 C=512 H=8 D=64, buckets=49. bf16 MFMA pipeline (threshold 0.106).
// rpe[b,h,t,s] == rpe_table[b//4, bucket[8*(b%4)+h, t, s]]
// R3: attn LDS 28.9KB (P overlays Qs), bucket-stage row perm (conflict-free
//     byte reads), tbl x4 quad replicas + log2-domain exp, trunc P store,
//     branchless 2x bucket kernel, merged wtrans, launch_bounds on TN=64 gemm.
// ---------------------------------------------------------------------------

typedef unsigned short ushort_t;
typedef __bf16 bf16x8 __attribute__((ext_vector_type(8)));
typedef float floatx4 __attribute__((ext_vector_type(4)));
typedef unsigned short ushort4v __attribute__((ext_vector_type(4)));
typedef unsigned short ushort8v __attribute__((ext_vector_type(8)));

#define DEV __device__ __forceinline__

#define B_ 32
#define T_ 500
#define C_ 512
#define H_ 8
#define M_ 16000      // B*T

// ---- workspace layout (bytes) ----
#define OFF_QKV    0ULL            // 16016*1536*2 = 49,201,152   (later: h 16000*1024*2)
#define OFF_XBF    49201152ULL     // 16,384,000                  (later: x1)
#define OFF_BUCKET 65585152ULL     // 8,000,000   u8 (32,500,500)
#define OFF_VT     73585152ULL     // 16,777,216  bf16 (32,8,64,512)
#define OFF_Y      90362368ULL     // 16,384,000  bf16 attn out
#define OFF_WATTN  106746368ULL    // 1,572,864   bf16 (1536,512) = w_attn^T
#define OFF_WPROJ  108319232ULL    // 524,288     bf16 (512,512)
#define OFF_WFC    108843520ULL    // 1,048,576   bf16 (1024,512)
#define OFF_WFC2   109892096ULL    // 1,048,576   bf16 (512,1024)

DEV ushort_t f2bf(float f) {
  union { float f; unsigned u; } v; v.f = f;
  unsigned r = v.u + 0x7fffu + ((v.u >> 16) & 1u);   // RNE
  return (ushort_t)(r >> 16);
}
DEV float bf2f(ushort_t u) {
  union { unsigned u; float f; } v; v.u = ((unsigned)u) << 16;
  return v.f;
}

DEV void gload16(const void* g, void* l) {
  __builtin_amdgcn_global_load_lds(
      (__attribute__((address_space(1))) void*)(g),
      (__attribute__((address_space(3))) void*)(l), 16, 0, 0);
}

// ---------------------------------------------------------------------------
__global__ __launch_bounds__(256) void cvt_bf16(const float* __restrict__ in,
                                                ushort_t* __restrict__ out, int n) {
  int i = (blockIdx.x * 256 + threadIdx.x) * 4;
  if (i >= n) return;
  float4 v = *(const float4*)(in + i);
  ushort4v o = { f2bf(v.x), f2bf(v.y), f2bf(v.z), f2bf(v.w) };
  *(ushort4v*)(out + i) = o;
}

// ---------------------------------------------------------------------------
// All four weight transposes in one launch. (K,N) fp32 -> (N,K) bf16.
// block counts: attn 48x16=768, proj 16x16=256, fc 32x16=512, fc2 16x32=512
// ---------------------------------------------------------------------------
struct WTDesc { const float* w; ushort_t* wt; int K; int N; };
struct WTArgs { WTDesc d[4]; };

__global__ __launch_bounds__(256) void wtrans_all(WTArgs a) {
  const int bid = blockIdx.x;
  int z, local;
  if (bid < 768)       { z = 0; local = bid; }
  else if (bid < 1024) { z = 1; local = bid - 768; }
  else if (bid < 1536) { z = 2; local = bid - 1024; }
  else                 { z = 3; local = bid - 1536; }
  const WTDesc dd = a.d[z];
  const int gx = dd.N >> 5;
  const int n0 = (local % gx) * 32, k0 = (local / gx) * 32;

  __shared__ float tile[32][33];
  const int c = threadIdx.x & 31, r = threadIdx.x >> 5;
#pragma unroll
  for (int rr = 0; rr < 4; ++rr)
    tile[r + rr * 8][c] = dd.w[(size_t)(k0 + r + rr * 8) * dd.N + n0 + c];
  __syncthreads();
#pragma unroll
  for (int rr = 0; rr < 4; ++rr)
    dd.wt[(size_t)(n0 + r + rr * 8) * dd.K + k0 + c] = f2bf(tile[c][r + rr * 8]);
}

// ---------------------------------------------------------------------------
// bucket ids: (32,500,500) u8.  grid (500, 32), 256 threads x 2 s, branchless.
// ---------------------------------------------------------------------------
__global__ __launch_bounds__(256) void bucket_kernel(const int* __restrict__ ct,
                                                     unsigned char* __restrict__ bucket) {
  const int t = blockIdx.x, b = blockIdx.y;
  const int2 a = ((const int2*)ct)[(size_t)b * T_ + t];
  const float ax = (float)a.x, ay = (float)a.y;
#pragma unroll
  for (int j = 0; j < 2; ++j) {
    const int s = threadIdx.x + j * 256;
    if (s < T_) {
      const int2 c2 = ((const int2*)ct)[(size_t)b * T_ + s];
      const float dx = ax - (float)c2.x, dy = ay - (float)c2.y;
      const float dist = sqrtf(dx * dx + dy * dy);
      const float rel = truncf(dist / 12.0f);
      const float far = fminf(rintf(12.0f + logf(rel / 12.0f) * (12.0f / 2.0794415416798357f)), 24.0f);
      const float idx = (rel <= 12.0f) ? rel : far;
      bucket[((size_t)b * T_ + t) * T_ + s] = (unsigned char)((int)idx + 24);
    }
  }
}

// ---------------------------------------------------------------------------
// GEMM: C(M x N) = A(M x K) * Bt(N x K)^T.  128 x TN tile, BK=64, xor-swizzled
// LDS (conflict-free b128 frag reads), 256 threads.
// TN=128: 2x2 waves (4x4 acc). TN=64: 4x1 waves (2x4 acc), 4 blocks/CU forced.
// EPI 0: bf16(acc+bias)  1: bf16(gelu)  2: f32(+resf)  3: f32(+bf2f(resb))
// ---------------------------------------------------------------------------
template <int TN, int EPI>
__global__ __launch_bounds__(256, TN == 64 ? 4 : 2)
void gemm_bt(const ushort_t* __restrict__ A,
             const ushort_t* __restrict__ Bt,
             const float* __restrict__ bias,
             const float* __restrict__ resf,
             const ushort_t* __restrict__ resb,
             void* __restrict__ outp,
             int N, int K) {
  constexpr int TMW = (TN == 128) ? 4 : 2;
  __shared__ __align__(16) ushort_t As[128 * 64];
  __shared__ __align__(16) ushort_t Bs[TN * 64];
  const int tid = threadIdx.x;
  const int lane = tid & 63, w = tid >> 6;
  const int wm = (TN == 128) ? (w >> 1) : w;
  const int wn = (TN == 128) ? (w & 1) : 0;
  const int quad = lane >> 4, l15 = lane & 15;
  const int m0 = blockIdx.y * 128, n0 = blockIdx.x * TN;

  floatx4 acc[TMW][4] = {};

  for (int k0 = 0; k0 < K; k0 += 64) {
    __syncthreads();
#pragma unroll
    for (int j = 0; j < 4; ++j) {
      const int chunk = j * 256 + tid;
      const int row = chunk >> 3, pos = chunk & 7, c = pos ^ (row & 7);
      gload16(A + (size_t)(m0 + row) * K + k0 + c * 8, (char*)As + j * 4096 + w * 1024);
    }
#pragma unroll
    for (int j = 0; j < TN / 32; ++j) {
      const int chunk = j * 256 + tid;
      const int row = chunk >> 3, pos = chunk & 7, c = pos ^ (row & 7);
      gload16(Bt + (size_t)(n0 + row) * K + k0 + c * 8, (char*)Bs + j * 4096 + w * 1024);
    }
    asm volatile("s_waitcnt vmcnt(0)" ::: "memory");
    __syncthreads();

#pragma unroll
    for (int kq = 0; kq < 2; ++kq) {
      bf16x8 af[TMW], bfr[4];
#pragma unroll
      for (int t = 0; t < TMW; ++t) {
        const int row = wm * (TMW * 16) + t * 16 + l15;
        const int pos = (kq * 4 + quad) ^ (row & 7);
        af[t] = *(const bf16x8*)((const char*)As + row * 128 + pos * 16);
      }
#pragma unroll
      for (int t = 0; t < 4; ++t) {
        const int row = wn * 64 + t * 16 + l15;
        const int pos = (kq * 4 + quad) ^ (row & 7);
        bfr[t] = *(const bf16x8*)((const char*)Bs + row * 128 + pos * 16);
      }
#pragma unroll
      for (int tm = 0; tm < TMW; ++tm)
#pragma unroll
        for (int tn = 0; tn < 4; ++tn)
          acc[tm][tn] = __builtin_amdgcn_mfma_f32_16x16x32_bf16(af[tm], bfr[tn], acc[tm][tn], 0, 0, 0);
    }
  }

#pragma unroll
  for (int tn = 0; tn < 4; ++tn) {
    const int n = n0 + wn * 64 + tn * 16 + l15;
    const float bs = bias[n];
#pragma unroll
    for (int tm = 0; tm < TMW; ++tm) {
#pragma unroll
      for (int r = 0; r < 4; ++r) {
        const int m = m0 + wm * (TMW * 16) + tm * 16 + quad * 4 + r;
        const float v = acc[tm][tn][r] + bs;
        if (EPI == 0) {
          ((ushort_t*)outp)[(size_t)m * N + n] = f2bf(v);
        } else if (EPI == 1) {
          const float gv = 0.5f * v * (1.0f + erff(v * 0.70710678118654752f));
          ((ushort_t*)outp)[(size_t)m * N + n] = f2bf(gv);
        } else if (EPI == 2) {
          ((float*)outp)[(size_t)m * N + n] = v + resf[(size_t)m * N + n];
        } else {
          ((float*)outp)[(size_t)m * N + n] = v + bf2f(resb[(size_t)m * N + n]);
        }
      }
    }
  }
}

// ---------------------------------------------------------------------------
// V transpose: qkv v-part (b,s,h*64+d) -> vt (b,h,d, s padded to 512)
// ---------------------------------------------------------------------------
__global__ __launch_bounds__(256) void vtrans_kernel(const ushort_t* __restrict__ qkv,
                                                     ushort_t* __restrict__ vt) {
  const int sc = blockIdx.x, h = blockIdx.y, b = blockIdx.z;
  __shared__ ushort_t tile[64][65];
  const int tid = threadIdx.x;
#pragma unroll
  for (int j = 0; j < 2; ++j) {
    const int L = j * 4096 + tid * 16;
    const int row = L >> 7, cel = (L & 127) >> 1;
    const ushort_t* src = qkv + (size_t)(b * T_ + sc * 64 + row) * 1536 + 1024 + h * 64 + cel;
    ushort8v val = *(const ushort8v*)src;
#pragma unroll
    for (int e = 0; e < 8; ++e) tile[row][cel + e] = val[e];
  }
  __syncthreads();
#pragma unroll
  for (int j = 0; j < 2; ++j) {
    const int L = j * 4096 + tid * 16;
    const int d = L >> 7, sb = (L & 127) >> 1;
    ushort8v ov;
#pragma unroll
    for (int e = 0; e < 8; ++e) {
      const int s = sc * 64 + sb + e;
      ov[e] = (s < T_) ? tile[sb + e][d] : (ushort_t)0;
    }
    *(ushort8v*)(vt + ((size_t)(b * 8 + h) * 64 + d) * 512 + sc * 64 + sb) = ov;
  }
}

// ---------------------------------------------------------------------------
// fused flash attention with RPE bias. No-max softmax, deferred row-sum.
// LDS 28.9 KB: P overlays Qs (wave-private, xor-swizzled); bucket staged with
// row-permuted DMA (conflict-free byte reads); tbl x4 quad replicas in
// log2-domain. grid 2048 flat (XCD-swizzled), 256 threads (4 waves x 16 rows).
// ---------------------------------------------------------------------------
__global__ __launch_bounds__(256, 5) void attn_kernel(const ushort_t* __restrict__ qkv,
                                                      const ushort_t* __restrict__ vt,
                                                      const unsigned char* __restrict__ bucket,
                                                      const float* __restrict__ rpe,
                                                      ushort_t* __restrict__ y) {
  const int bid = blockIdx.x;
  const int xcd = bid & 7, sl = bid >> 3;
  const int qt = sl & 7;
  const int pair = xcd * 32 + (sl >> 3);
  const int h = pair >> 5, b = pair & 31;
  const int g = b >> 2;
  const int bpp = 8 * (b & 3) + h;

  __shared__ __align__(16) ushort_t Qs[64 * 64];    // reused as P after qf load
  __shared__ __align__(16) ushort_t Ks[64 * 64];
  __shared__ __align__(16) ushort_t VTs[64 * 64];
  __shared__ __align__(16) unsigned char bkS[64 * 64];  // row-permuted
  __shared__ float tbl2[224];                       // 4 quad replicas, stride 52

  const int tid = threadIdx.x;
  const int lane = tid & 63, w = tid >> 6;
  const int quad = lane >> 4, l15 = lane & 15;
  const int t0 = qt * 64;

  // stage Q tile (xor-swizzled)
#pragma unroll
  for (int j = 0; j < 2; ++j) {
    const int chunk = j * 256 + tid;
    const int row = chunk >> 3, pos = chunk & 7, c = pos ^ (row & 7);
    gload16(qkv + (size_t)(b * T_ + t0 + row) * 1536 + h * 64 + c * 8,
            (char*)Qs + j * 4096 + w * 1024);
  }
  if (tid < 224) {
    const int q = tid / 52, i = tid - q * 52;
    tbl2[tid] = (q < 4 && i < 49) ? rpe[g * 49 + i] * 1.44269504f : 0.0f;
  }
  asm volatile("s_waitcnt vmcnt(0)" ::: "memory");
  __syncthreads();

  bf16x8 qf[2];
#pragma unroll
  for (int kq = 0; kq < 2; ++kq) {
    const int row = w * 16 + l15;
    const int pos = (kq * 4 + quad) ^ (row & 7);
    qf[kq] = *(const bf16x8*)((const char*)Qs + row * 128 + pos * 16);
  }

  floatx4 o[4] = {};
  float lsum[4] = {0.0f, 0.0f, 0.0f, 0.0f};
  char* pw = (char*)Qs + w * 2048;   // wave-private P region (16 rows x 128 B)

  // bucket DMA row permutation: lane l stages global row w*16+((l>>2)&3)*4+(l>>4)
  const int bk_gq = (lane >> 2) & 3, bk_gr = lane >> 4, bk_pos = lane & 3;
  const int bk_grow = w * 16 + bk_gq * 4 + bk_gr;

  for (int st = 0; st < 8; ++st) {
    const int s0 = st * 64;
    __syncthreads();   // protect Ks/VTs/bkS from previous iteration's readers
#pragma unroll
    for (int j = 0; j < 2; ++j) {
      const int chunk = j * 256 + tid;
      const int row = chunk >> 3, pos = chunk & 7, c = pos ^ (row & 7);
      gload16(qkv + (size_t)(b * T_ + s0 + row) * 1536 + 512 + h * 64 + c * 8,
              (char*)Ks + j * 4096 + w * 1024);
      gload16(vt + ((size_t)(b * 8 + h) * 64 + row) * 512 + s0 + c * 8,
              (char*)VTs + j * 4096 + w * 1024);
    }
    {
      const int tr = t0 + bk_grow;
      const int trc = (tr < T_) ? tr : (T_ - 1);
      gload16(bucket + (size_t)bpp * 250000 + (size_t)trc * 500 + s0 + bk_pos * 16,
              (char*)bkS + w * 1024);
    }
    asm volatile("s_waitcnt vmcnt(0)" ::: "memory");
    __syncthreads();

    // QK^T
    floatx4 sc[4];
#pragma unroll
    for (int tn = 0; tn < 4; ++tn) {
      floatx4 z = {0.0f, 0.0f, 0.0f, 0.0f};
#pragma unroll
      for (int kq = 0; kq < 2; ++kq) {
        const int row = tn * 16 + l15;
        const int pos = (kq * 4 + quad) ^ (row & 7);
        const bf16x8 kf = *(const bf16x8*)((const char*)Ks + row * 128 + pos * 16);
        z = __builtin_amdgcn_mfma_f32_16x16x32_bf16(qf[kq], kf, z, 0, 0, 0);
      }
      sc[tn] = z;
    }

    // P = exp2(score*0.125*log2e + tbl2[bucket]); trunc-store bf16 into pw
#pragma unroll
    for (int r = 0; r < 4; ++r) {
      const int prow = quad * 4 + r;
      const int bkbase = (w * 16 + r * 4 + quad) * 64;   // permuted LDS row
#pragma unroll
      for (int tn = 0; tn < 4; ++tn) {
        const int scol = s0 + tn * 16 + l15;
        const int idx = bkS[bkbase + tn * 16 + l15] & 63;
        const float val = fmaf(sc[tn][r], 0.18033688f, tbl2[quad * 52 + idx]);
        const float p = (scol < T_) ? exp2f(val) : 0.0f;
        lsum[r] += p;
        const int chunk = (tn * 2 + (l15 >> 3)) ^ (prow & 7);
        *(ushort_t*)(pw + prow * 128 + chunk * 16 + (l15 & 7) * 2) =
            (ushort_t)(__builtin_bit_cast(unsigned, p) >> 16);   // trunc bf16
      }
    }
    asm volatile("" ::: "memory");   // order P stores before same-wave frag reads

    // PV
#pragma unroll
    for (int ks = 0; ks < 2; ++ks) {
      const int ppos = (ks * 4 + quad) ^ (l15 & 7);
      const bf16x8 pf = *(const bf16x8*)(pw + l15 * 128 + ppos * 16);
#pragma unroll
      for (int nd = 0; nd < 4; ++nd) {
        const int row = nd * 16 + l15;
        const int pos = (ks * 4 + quad) ^ (row & 7);
        const bf16x8 vf = *(const bf16x8*)((const char*)VTs + row * 128 + pos * 16);
        o[nd] = __builtin_amdgcn_mfma_f32_16x16x32_bf16(pf, vf, o[nd], 0, 0, 0);
      }
    }
  }

  // deferred row-sum reduce + write
#pragma unroll
  for (int r = 0; r < 4; ++r) {
    float s = lsum[r];
    s += __shfl_xor(s, 1);
    s += __shfl_xor(s, 2);
    s += __shfl_xor(s, 4);
    s += __shfl_xor(s, 8);
    const int t = t0 + w * 16 + quad * 4 + r;
    if (t < T_) {
      const float inv = 1.0f / s;
#pragma unroll
      for (int nd = 0; nd < 4; ++nd)
        y[((size_t)b * T_ + t) * 512 + h * 64 + nd * 16 + l15] = f2bf(o[nd][r] * inv);
    }
  }
}

// ---------------------------------------------------------------------------
__global__ __launch_bounds__(256) void ln_kernel(const float* z,
                                                 const float* __restrict__ gw,
                                                 const float* __restrict__ gb,
                                                 ushort_t* out_bf, float* out_f) {
  const int row = blockIdx.x;
  const int tid = threadIdx.x, lane = tid & 63, w = tid >> 6;
  const float* zr = z + (size_t)row * 512;
  const float2 v = *(const float2*)(zr + tid * 2);
  float s = v.x + v.y;
#pragma unroll
  for (int m = 1; m < 64; m <<= 1) s += __shfl_xor(s, m);
  __shared__ float red[8];
  if (lane == 0) red[w] = s;
  __syncthreads();
  const float mean = (red[0] + red[1] + red[2] + red[3]) * (1.0f / 512.0f);
  const float d0 = v.x - mean, d1 = v.y - mean;
  float q = d0 * d0 + d1 * d1;
#pragma unroll
  for (int m = 1; m < 64; m <<= 1) q += __shfl_xor(q, m);
  if (lane == 0) red[4 + w] = q;
  __syncthreads();
  const float var = (red[4] + red[5] + red[6] + red[7]) * (1.0f / 512.0f);
  const float rstd = rsqrtf(var + 1e-5f);
  const int c0 = tid * 2;
  const float o0 = d0 * rstd * gw[c0] + gb[c0];
  const float o1 = d1 * rstd * gw[c0 + 1] + gb[c0 + 1];
  if (out_bf) {
    out_bf[(size_t)row * 512 + c0] = f2bf(o0);
    out_bf[(size_t)row * 512 + c0 + 1] = f2bf(o1);
  }
  if (out_f) {
    float2 ov; ov.x = o0; ov.y = o1;
    *(float2*)(out_f + (size_t)row * 512 + c0) = ov;
  }
}

// ---------------------------------------------------------------------------
extern "C" void kernel_launch(void* const* d_in, const int* in_sizes, int n_in,
                              void* d_out, int out_size, void* d_ws, size_t ws_size,
                              hipStream_t stream) {
  (void)in_sizes; (void)n_in; (void)out_size; (void)ws_size;
  const float* x      = (const float*)d_in[0];
  const int*   ct     = (const int*)d_in[1];
  const float* w_attn = (const float*)d_in[2];
  const float* b_attn = (const float*)d_in[3];
  const float* w_proj = (const float*)d_in[4];
  const float* b_proj = (const float*)d_in[5];
  const float* rpe    = (const float*)d_in[6];
  const float* ln1w   = (const float*)d_in[7];
  const float* ln1b   = (const float*)d_in[8];
  const float* ln2w   = (const float*)d_in[9];
  const float* ln2b   = (const float*)d_in[10];
  const float* w_fc   = (const float*)d_in[11];
  const float* b_fc   = (const float*)d_in[12];
  const float* w_fc2  = (const float*)d_in[13];
  const float* b_fc2  = (const float*)d_in[14];
  float* out = (float*)d_out;

  char* ws = (char*)d_ws;
  ushort_t* qkv     = (ushort_t*)(ws + OFF_QKV);
  ushort_t* h_buf   = (ushort_t*)(ws + OFF_QKV);
  ushort_t* x_bf    = (ushort_t*)(ws + OFF_XBF);
  ushort_t* x1      = (ushort_t*)(ws + OFF_XBF);
  unsigned char* bk = (unsigned char*)(ws + OFF_BUCKET);
  ushort_t* vt      = (ushort_t*)(ws + OFF_VT);
  ushort_t* y       = (ushort_t*)(ws + OFF_Y);
  ushort_t* wt_attn = (ushort_t*)(ws + OFF_WATTN);
  ushort_t* wt_proj = (ushort_t*)(ws + OFF_WPROJ);
  ushort_t* wt_fc   = (ushort_t*)(ws + OFF_WFC);
  ushort_t* wt_fc2  = (ushort_t*)(ws + OFF_WFC2);

  cvt_bf16<<<dim3(8000), 256, 0, stream>>>(x, x_bf, M_ * C_);
  WTArgs wta;
  wta.d[0] = { w_attn, wt_attn, 512, 1536 };
  wta.d[1] = { w_proj, wt_proj, 512, 512 };
  wta.d[2] = { w_fc,   wt_fc,   512, 1024 };
  wta.d[3] = { w_fc2,  wt_fc2,  1024, 512 };
  wtrans_all<<<dim3(2048), 256, 0, stream>>>(wta);
  bucket_kernel<<<dim3(500, 32), 256, 0, stream>>>(ct, bk);

  // qkv = x @ w_attn + b_attn
  gemm_bt<128, 0><<<dim3(12, 125), 256, 0, stream>>>(x_bf, wt_attn, b_attn, nullptr, nullptr, qkv, 1536, 512);
  vtrans_kernel<<<dim3(8, 8, 32), 256, 0, stream>>>(qkv, vt);
  attn_kernel<<<dim3(2048), 256, 0, stream>>>(qkv, vt, bk, rpe, y);
  // z = x + y @ w_proj + b_proj  (f32, into d_out)
  gemm_bt<64, 2><<<dim3(8, 125), 256, 0, stream>>>(y, wt_proj, b_proj, x, nullptr, out, 512, 512);
  ln_kernel<<<dim3(16000), 256, 0, stream>>>(out, ln1w, ln1b, x1, nullptr);
  // h = gelu(x1 @ w_fc + b_fc)
  gemm_bt<128, 1><<<dim3(8, 125), 256, 0, stream>>>(x1, wt_fc, b_fc, nullptr, nullptr, h_buf, 1024, 512);
  // z2 = x1 + h @ w_fc2 + b_fc2
  gemm_bt<64, 3><<<dim3(8, 125), 256, 0, stream>>>(h_buf, wt_fc2, b_fc2, nullptr, x1, out, 512, 1024);
  ln_kernel<<<dim3(16000), 256, 0, stream>>>(out, ln2w, ln2b, nullptr, out);
}

// Round 4
// 351.521 us; speedup vs baseline: 1.1991x; 1.0169x over previous
//
#include <hip/hip_runtime.h>
#include <cstdint>
#include <cstddef>

// ---------------------------------------------------------------------------
// Block_85375359910651: RPE-attention transformer block on gfx950.
// B=32 T=500 C=512 H=8 D=64, buckets=49. bf16 MFMA pipeline (threshold 0.106).
// rpe[b,h,t,s] == rpe_table[b//4, bucket[8*(b%4)+h, t, s]]
// R4: attn is LDS-pipe-bound -> bucket moved off LDS (pre-permuted global
//     dword reads), vtrans fused into qkv-GEMM epilogue (packed 8B vt stores),
//     dedicated (M,1024) QK buffer, LDS 25.5KB.
// ---------------------------------------------------------------------------

typedef unsigned short ushort_t;
typedef __bf16 bf16x8 __attribute__((ext_vector_type(8)));
typedef float floatx4 __attribute__((ext_vector_type(4)));
typedef unsigned short ushort4v __attribute__((ext_vector_type(4)));
typedef unsigned short ushort8v __attribute__((ext_vector_type(8)));

#define DEV __device__ __forceinline__

#define B_ 32
#define T_ 500
#define C_ 512
#define H_ 8
#define M_ 16000      // B*T

// ---- workspace layout (bytes), total ~94.7 MB ----
#define OFF_QK     0ULL            // 16016*1024*2 = 32,800,768  (later: h 16000*1024*2)
#define OFF_XBF    32800768ULL     // 16,384,000                 (later: x1)
#define OFF_BUCKET 49184768ULL     // 8,192,000   u8 (32,500,512) permuted
#define OFF_VT     57376768ULL     // 16,777,216  bf16 (32,8,64,512)
#define OFF_Y      74153984ULL     // 16,384,000  bf16 attn out
#define OFF_WATTN  90537984ULL     // 1,572,864   bf16 (1536,512)
#define OFF_WPROJ  92110848ULL     // 524,288     bf16 (512,512)
#define OFF_WFC    92635136ULL     // 1,048,576   bf16 (1024,512)
#define OFF_WFC2   93683712ULL     // 1,048,576   bf16 (512,1024)
#define VT_BYTES   16777216ULL

DEV ushort_t f2bf(float f) {
  union { float f; unsigned u; } v; v.f = f;
  unsigned r = v.u + 0x7fffu + ((v.u >> 16) & 1u);   // RNE
  return (ushort_t)(r >> 16);
}
DEV float bf2f(ushort_t u) {
  union { unsigned u; float f; } v; v.u = ((unsigned)u) << 16;
  return v.f;
}

DEV void gload16(const void* g, void* l) {
  __builtin_amdgcn_global_load_lds(
      (__attribute__((address_space(1))) void*)(g),
      (__attribute__((address_space(3))) void*)(l), 16, 0, 0);
}

// ---------------------------------------------------------------------------
__global__ __launch_bounds__(256) void cvt_bf16(const float* __restrict__ in,
                                                ushort_t* __restrict__ out, int n) {
  int i = (blockIdx.x * 256 + threadIdx.x) * 4;
  if (i >= n) return;
  float4 v = *(const float4*)(in + i);
  ushort4v o = { f2bf(v.x), f2bf(v.y), f2bf(v.z), f2bf(v.w) };
  *(ushort4v*)(out + i) = o;
}

// ---------------------------------------------------------------------------
// All four weight transposes in one launch. (K,N) fp32 -> (N,K) bf16.
// ---------------------------------------------------------------------------
struct WTDesc { const float* w; ushort_t* wt; int K; int N; };
struct WTArgs { WTDesc d[4]; };

__global__ __launch_bounds__(256) void wtrans_all(WTArgs a) {
  const int bid = blockIdx.x;
  int z, local;
  if (bid < 768)       { z = 0; local = bid; }
  else if (bid < 1024) { z = 1; local = bid - 768; }
  else if (bid < 1536) { z = 2; local = bid - 1024; }
  else                 { z = 3; local = bid - 1536; }
  const WTDesc dd = a.d[z];
  const int gx = dd.N >> 5;
  const int n0 = (local % gx) * 32, k0 = (local / gx) * 32;

  __shared__ float tile[32][33];
  const int c = threadIdx.x & 31, r = threadIdx.x >> 5;
#pragma unroll
  for (int rr = 0; rr < 4; ++rr)
    tile[r + rr * 8][c] = dd.w[(size_t)(k0 + r + rr * 8) * dd.N + n0 + c];
  __syncthreads();
#pragma unroll
  for (int rr = 0; rr < 4; ++rr)
    dd.wt[(size_t)(n0 + r + rr * 8) * dd.K + k0 + c] = f2bf(tile[c][r + rr * 8]);
}

// ---------------------------------------------------------------------------
// bucket ids, PERMUTED layout: row stride 512; within 64-col block, byte at
// (s&15)*4 + ((s>>4)&3) holds column s. Consumer lane l15 reads one dword at
// blk*64 + l15*4 and gets cols {0,16,32,48}+l15 in bytes 0..3.
// ---------------------------------------------------------------------------
__global__ __launch_bounds__(256) void bucket_kernel(const int* __restrict__ ct,
                                                     unsigned char* __restrict__ bucket) {
  const int t = blockIdx.x, b = blockIdx.y;
  const int2 a = ((const int2*)ct)[(size_t)b * T_ + t];
  const float ax = (float)a.x, ay = (float)a.y;
#pragma unroll
  for (int j = 0; j < 2; ++j) {
    const int s = threadIdx.x + j * 256;
    if (s < T_) {
      const int2 c2 = ((const int2*)ct)[(size_t)b * T_ + s];
      const float dx = ax - (float)c2.x, dy = ay - (float)c2.y;
      const float dist = sqrtf(dx * dx + dy * dy);
      const float rel = truncf(dist / 12.0f);
      const float far = fminf(rintf(12.0f + logf(rel / 12.0f) * (12.0f / 2.0794415416798357f)), 24.0f);
      const float idx = (rel <= 12.0f) ? rel : far;
      bucket[((size_t)(b * T_ + t) << 9) + (s >> 6) * 64 + (s & 15) * 4 + ((s >> 4) & 3)]
          = (unsigned char)((int)idx + 24);
    }
  }
}

// ---------------------------------------------------------------------------
// qkv GEMM with fused V-transpose epilogue. A(M x 512) * Wt(1536 x 512)^T.
// 128x128 tile, BK=64, xor-swizzled LDS. Q,K cols -> qk (M x 1024) bf16;
// V cols -> vt (b,h,d, s[512]) as packed 8B stores (4|m-base and 4|500 =>
// the 4-row pack never crosses a batch boundary).
// ---------------------------------------------------------------------------
__global__ __launch_bounds__(256, 2)
void gemm_qkv(const ushort_t* __restrict__ A,
              const ushort_t* __restrict__ Bt,
              const float* __restrict__ bias,
              ushort_t* __restrict__ qk,
              ushort_t* __restrict__ vt) {
  constexpr int K = 512;
  __shared__ __align__(16) ushort_t As[128 * 64];
  __shared__ __align__(16) ushort_t Bs[128 * 64];
  const int tid = threadIdx.x;
  const int lane = tid & 63, w = tid >> 6;
  const int wm = w >> 1, wn = w & 1;
  const int quad = lane >> 4, l15 = lane & 15;
  const int m0 = blockIdx.y * 128, n0 = blockIdx.x * 128;

  floatx4 acc[4][4] = {};

  for (int k0 = 0; k0 < K; k0 += 64) {
    __syncthreads();
#pragma unroll
    for (int j = 0; j < 4; ++j) {
      const int chunk = j * 256 + tid;
      const int row = chunk >> 3, pos = chunk & 7, c = pos ^ (row & 7);
      gload16(A + (size_t)(m0 + row) * K + k0 + c * 8, (char*)As + j * 4096 + w * 1024);
      gload16(Bt + (size_t)(n0 + row) * K + k0 + c * 8, (char*)Bs + j * 4096 + w * 1024);
    }
    asm volatile("s_waitcnt vmcnt(0)" ::: "memory");
    __syncthreads();

#pragma unroll
    for (int kq = 0; kq < 2; ++kq) {
      bf16x8 af[4], bfr[4];
#pragma unroll
      for (int t = 0; t < 4; ++t) {
        const int rowa = wm * 64 + t * 16 + l15;
        const int posa = (kq * 4 + quad) ^ (rowa & 7);
        af[t] = *(const bf16x8*)((const char*)As + rowa * 128 + posa * 16);
        const int rowb = wn * 64 + t * 16 + l15;
        const int posb = (kq * 4 + quad) ^ (rowb & 7);
        bfr[t] = *(const bf16x8*)((const char*)Bs + rowb * 128 + posb * 16);
      }
#pragma unroll
      for (int tm = 0; tm < 4; ++tm)
#pragma unroll
        for (int tn = 0; tn < 4; ++tn)
          acc[tm][tn] = __builtin_amdgcn_mfma_f32_16x16x32_bf16(af[tm], bfr[tn], acc[tm][tn], 0, 0, 0);
    }
  }

  if (n0 < 1024) {   // Q,K path (uniform per block)
#pragma unroll
    for (int tn = 0; tn < 4; ++tn) {
      const int n = n0 + wn * 64 + tn * 16 + l15;
      const float bs = bias[n];
#pragma unroll
      for (int tm = 0; tm < 4; ++tm)
#pragma unroll
        for (int r = 0; r < 4; ++r) {
          const int m = m0 + wm * 64 + tm * 16 + quad * 4 + r;
          qk[(size_t)m * 1024 + n] = f2bf(acc[tm][tn][r] + bs);
        }
    }
  } else {           // V path: transpose into vt
#pragma unroll
    for (int tn = 0; tn < 4; ++tn) {
      const int n = n0 + wn * 64 + tn * 16 + l15;
      const float bs = bias[n];
      const int hh = (n >> 6) - 16, dd = n & 63;
#pragma unroll
      for (int tm = 0; tm < 4; ++tm) {
        const int mb = m0 + wm * 64 + tm * 16 + quad * 4;
        const int bb = mb / 500;
        const int ss = mb - bb * 500;
        ushort4v pk;
#pragma unroll
        for (int r = 0; r < 4; ++r) pk[r] = f2bf(acc[tm][tn][r] + bs);
        *(ushort4v*)(vt + (((size_t)(bb * 8 + hh)) * 64 + dd) * 512 + ss) = pk;
      }
    }
  }
}

// ---------------------------------------------------------------------------
// GEMM: C(M x N) = A(M x K) * Bt(N x K)^T.  128 x TN tile, BK=64.
// EPI 1: bf16(gelu(acc+bias))  2: f32(+resf)  3: f32(+bf2f(resb))
// ---------------------------------------------------------------------------
template <int TN, int EPI>
__global__ __launch_bounds__(256, TN == 64 ? 4 : 2)
void gemm_bt(const ushort_t* __restrict__ A,
             const ushort_t* __restrict__ Bt,
             const float* __restrict__ bias,
             const float* __restrict__ resf,
             const ushort_t* __restrict__ resb,
             void* __restrict__ outp,
             int N, int K) {
  constexpr int TMW = (TN == 128) ? 4 : 2;
  __shared__ __align__(16) ushort_t As[128 * 64];
  __shared__ __align__(16) ushort_t Bs[TN * 64];
  const int tid = threadIdx.x;
  const int lane = tid & 63, w = tid >> 6;
  const int wm = (TN == 128) ? (w >> 1) : w;
  const int wn = (TN == 128) ? (w & 1) : 0;
  const int quad = lane >> 4, l15 = lane & 15;
  const int m0 = blockIdx.y * 128, n0 = blockIdx.x * TN;

  floatx4 acc[TMW][4] = {};

  for (int k0 = 0; k0 < K; k0 += 64) {
    __syncthreads();
#pragma unroll
    for (int j = 0; j < 4; ++j) {
      const int chunk = j * 256 + tid;
      const int row = chunk >> 3, pos = chunk & 7, c = pos ^ (row & 7);
      gload16(A + (size_t)(m0 + row) * K + k0 + c * 8, (char*)As + j * 4096 + w * 1024);
    }
#pragma unroll
    for (int j = 0; j < TN / 32; ++j) {
      const int chunk = j * 256 + tid;
      const int row = chunk >> 3, pos = chunk & 7, c = pos ^ (row & 7);
      gload16(Bt + (size_t)(n0 + row) * K + k0 + c * 8, (char*)Bs + j * 4096 + w * 1024);
    }
    asm volatile("s_waitcnt vmcnt(0)" ::: "memory");
    __syncthreads();

#pragma unroll
    for (int kq = 0; kq < 2; ++kq) {
      bf16x8 af[TMW], bfr[4];
#pragma unroll
      for (int t = 0; t < TMW; ++t) {
        const int row = wm * (TMW * 16) + t * 16 + l15;
        const int pos = (kq * 4 + quad) ^ (row & 7);
        af[t] = *(const bf16x8*)((const char*)As + row * 128 + pos * 16);
      }
#pragma unroll
      for (int t = 0; t < 4; ++t) {
        const int row = wn * 64 + t * 16 + l15;
        const int pos = (kq * 4 + quad) ^ (row & 7);
        bfr[t] = *(const bf16x8*)((const char*)Bs + row * 128 + pos * 16);
      }
#pragma unroll
      for (int tm = 0; tm < TMW; ++tm)
#pragma unroll
        for (int tn = 0; tn < 4; ++tn)
          acc[tm][tn] = __builtin_amdgcn_mfma_f32_16x16x32_bf16(af[tm], bfr[tn], acc[tm][tn], 0, 0, 0);
    }
  }

#pragma unroll
  for (int tn = 0; tn < 4; ++tn) {
    const int n = n0 + wn * 64 + tn * 16 + l15;
    const float bs = bias[n];
#pragma unroll
    for (int tm = 0; tm < TMW; ++tm) {
#pragma unroll
      for (int r = 0; r < 4; ++r) {
        const int m = m0 + wm * (TMW * 16) + tm * 16 + quad * 4 + r;
        const float v = acc[tm][tn][r] + bs;
        if (EPI == 1) {
          const float gv = 0.5f * v * (1.0f + erff(v * 0.70710678118654752f));
          ((ushort_t*)outp)[(size_t)m * N + n] = f2bf(gv);
        } else if (EPI == 2) {
          ((float*)outp)[(size_t)m * N + n] = v + resf[(size_t)m * N + n];
        } else {
          ((float*)outp)[(size_t)m * N + n] = v + bf2f(resb[(size_t)m * N + n]);
        }
      }
    }
  }
}

// ---------------------------------------------------------------------------
// fused flash attention with RPE bias. No-max softmax, deferred row-sum.
// LDS 25.5 KB: Qs(->P overlay), Ks, VTs, tbl2. Bucket read directly from
// global (pre-permuted dwords). grid 2048 flat (XCD-swizzled), 4 waves.
// ---------------------------------------------------------------------------
__global__ __launch_bounds__(256, 5) void attn_kernel(const ushort_t* __restrict__ qk,
                                                      const ushort_t* __restrict__ vt,
                                                      const unsigned char* __restrict__ bucket,
                                                      const float* __restrict__ rpe,
                                                      ushort_t* __restrict__ y) {
  const int bid = blockIdx.x;
  const int xcd = bid & 7, sl = bid >> 3;
  const int qt = sl & 7;
  const int pair = xcd * 32 + (sl >> 3);
  const int h = pair >> 5, b = pair & 31;
  const int g = b >> 2;
  const int bpp = 8 * (b & 3) + h;

  __shared__ __align__(16) ushort_t Qs[64 * 64];    // reused as P after qf load
  __shared__ __align__(16) ushort_t Ks[64 * 64];
  __shared__ __align__(16) ushort_t VTs[64 * 64];
  __shared__ float tbl2[224];                       // 4 quad replicas, stride 52

  const int tid = threadIdx.x;
  const int lane = tid & 63, w = tid >> 6;
  const int quad = lane >> 4, l15 = lane & 15;
  const int t0 = qt * 64;

#pragma unroll
  for (int j = 0; j < 2; ++j) {
    const int chunk = j * 256 + tid;
    const int row = chunk >> 3, pos = chunk & 7, c = pos ^ (row & 7);
    gload16(qk + (size_t)(b * T_ + t0 + row) * 1024 + h * 64 + c * 8,
            (char*)Qs + j * 4096 + w * 1024);
  }
  if (tid < 224) {
    const int q = tid / 52, i = tid - q * 52;
    tbl2[tid] = (q < 4 && i < 49) ? rpe[g * 49 + i] * 1.44269504f : 0.0f;
  }
  asm volatile("s_waitcnt vmcnt(0)" ::: "memory");
  __syncthreads();

  bf16x8 qf[2];
#pragma unroll
  for (int kq = 0; kq < 2; ++kq) {
    const int row = w * 16 + l15;
    const int pos = (kq * 4 + quad) ^ (row & 7);
    qf[kq] = *(const bf16x8*)((const char*)Qs + row * 128 + pos * 16);
  }

  floatx4 o[4] = {};
  float lsum[4] = {0.0f, 0.0f, 0.0f, 0.0f};
  char* pw = (char*)Qs + w * 2048;   // wave-private P region (16 rows x 128 B)

  // bucket row base addresses for this lane's 4 q-rows (clamped)
  const unsigned char* bkbase[4];
#pragma unroll
  for (int r = 0; r < 4; ++r) {
    const int tr = t0 + w * 16 + quad * 4 + r;
    const int trc = (tr < T_) ? tr : (T_ - 1);
    bkbase[r] = bucket + ((size_t)(bpp * T_ + trc) << 9) + (l15 << 2);
  }

  for (int st = 0; st < 8; ++st) {
    const int s0 = st * 64;
    __syncthreads();   // protect Ks/VTs from previous iteration's readers
#pragma unroll
    for (int j = 0; j < 2; ++j) {
      const int chunk = j * 256 + tid;
      const int row = chunk >> 3, pos = chunk & 7, c = pos ^ (row & 7);
      gload16(qk + (size_t)(b * T_ + s0 + row) * 1024 + 512 + h * 64 + c * 8,
              (char*)Ks + j * 4096 + w * 1024);
      gload16(vt + ((size_t)(b * 8 + h) * 64 + row) * 512 + s0 + c * 8,
              (char*)VTs + j * 4096 + w * 1024);
    }
    // bucket dwords: 4 tn-values per q-row packed per dword (permuted layout)
    unsigned bw[4];
#pragma unroll
    for (int r = 0; r < 4; ++r) bw[r] = *(const unsigned*)(bkbase[r] + s0);
    asm volatile("s_waitcnt vmcnt(0)" ::: "memory");
    __syncthreads();

    // QK^T
    floatx4 sc[4];
#pragma unroll
    for (int tn = 0; tn < 4; ++tn) {
      floatx4 z = {0.0f, 0.0f, 0.0f, 0.0f};
#pragma unroll
      for (int kq = 0; kq < 2; ++kq) {
        const int row = tn * 16 + l15;
        const int pos = (kq * 4 + quad) ^ (row & 7);
        const bf16x8 kf = *(const bf16x8*)((const char*)Ks + row * 128 + pos * 16);
        z = __builtin_amdgcn_mfma_f32_16x16x32_bf16(qf[kq], kf, z, 0, 0, 0);
      }
      sc[tn] = z;
    }

    // P = exp2(score*0.125*log2e + tbl2[bucket]); trunc-store bf16 into pw
#pragma unroll
    for (int r = 0; r < 4; ++r) {
      const int prow = quad * 4 + r;
#pragma unroll
      for (int tn = 0; tn < 4; ++tn) {
        const int scol = s0 + tn * 16 + l15;
        const int idx = (bw[r] >> (tn * 8)) & 63;
        const float val = fmaf(sc[tn][r], 0.18033688f, tbl2[quad * 52 + idx]);
        const float p = (scol < T_) ? exp2f(val) : 0.0f;
        lsum[r] += p;
        const int chunk = (tn * 2 + (l15 >> 3)) ^ (prow & 7);
        *(ushort_t*)(pw + prow * 128 + chunk * 16 + (l15 & 7) * 2) =
            (ushort_t)(__builtin_bit_cast(unsigned, p) >> 16);   // trunc bf16
      }
    }
    asm volatile("" ::: "memory");   // order P stores before same-wave frag reads

    // PV
#pragma unroll
    for (int ks = 0; ks < 2; ++ks) {
      const int ppos = (ks * 4 + quad) ^ (l15 & 7);
      const bf16x8 pf = *(const bf16x8*)(pw + l15 * 128 + ppos * 16);
#pragma unroll
      for (int nd = 0; nd < 4; ++nd) {
        const int row = nd * 16 + l15;
        const int pos = (ks * 4 + quad) ^ (row & 7);
        const bf16x8 vf = *(const bf16x8*)((const char*)VTs + row * 128 + pos * 16);
        o[nd] = __builtin_amdgcn_mfma_f32_16x16x32_bf16(pf, vf, o[nd], 0, 0, 0);
      }
    }
  }

  // deferred row-sum reduce + write
#pragma unroll
  for (int r = 0; r < 4; ++r) {
    float s = lsum[r];
    s += __shfl_xor(s, 1);
    s += __shfl_xor(s, 2);
    s += __shfl_xor(s, 4);
    s += __shfl_xor(s, 8);
    const int t = t0 + w * 16 + quad * 4 + r;
    if (t < T_) {
      const float inv = 1.0f / s;
#pragma unroll
      for (int nd = 0; nd < 4; ++nd)
        y[((size_t)b * T_ + t) * 512 + h * 64 + nd * 16 + l15] = f2bf(o[nd][r] * inv);
    }
  }
}

// ---------------------------------------------------------------------------
__global__ __launch_bounds__(256) void ln_kernel(const float* z,
                                                 const float* __restrict__ gw,
                                                 const float* __restrict__ gb,
                                                 ushort_t* out_bf, float* out_f) {
  const int row = blockIdx.x;
  const int tid = threadIdx.x, lane = tid & 63, w = tid >> 6;
  const float* zr = z + (size_t)row * 512;
  const float2 v = *(const float2*)(zr + tid * 2);
  float s = v.x + v.y;
#pragma unroll
  for (int m = 1; m < 64; m <<= 1) s += __shfl_xor(s, m);
  __shared__ float red[8];
  if (lane == 0) red[w] = s;
  __syncthreads();
  const float mean = (red[0] + red[1] + red[2] + red[3]) * (1.0f / 512.0f);
  const float d0 = v.x - mean, d1 = v.y - mean;
  float q = d0 * d0 + d1 * d1;
#pragma unroll
  for (int m = 1; m < 64; m <<= 1) q += __shfl_xor(q, m);
  if (lane == 0) red[4 + w] = q;
  __syncthreads();
  const float var = (red[4] + red[5] + red[6] + red[7]) * (1.0f / 512.0f);
  const float rstd = rsqrtf(var + 1e-5f);
  const int c0 = tid * 2;
  const float o0 = d0 * rstd * gw[c0] + gb[c0];
  const float o1 = d1 * rstd * gw[c0 + 1] + gb[c0 + 1];
  if (out_bf) {
    out_bf[(size_t)row * 512 + c0] = f2bf(o0);
    out_bf[(size_t)row * 512 + c0 + 1] = f2bf(o1);
  }
  if (out_f) {
    float2 ov; ov.x = o0; ov.y = o1;
    *(float2*)(out_f + (size_t)row * 512 + c0) = ov;
  }
}

// ---------------------------------------------------------------------------
extern "C" void kernel_launch(void* const* d_in, const int* in_sizes, int n_in,
                              void* d_out, int out_size, void* d_ws, size_t ws_size,
                              hipStream_t stream) {
  (void)in_sizes; (void)n_in; (void)out_size; (void)ws_size;
  const float* x      = (const float*)d_in[0];
  const int*   ct     = (const int*)d_in[1];
  const float* w_attn = (const float*)d_in[2];
  const float* b_attn = (const float*)d_in[3];
  const float* w_proj = (const float*)d_in[4];
  const float* b_proj = (const float*)d_in[5];
  const float* rpe    = (const float*)d_in[6];
  const float* ln1w   = (const float*)d_in[7];
  const float* ln1b   = (const float*)d_in[8];
  const float* ln2w   = (const float*)d_in[9];
  const float* ln2b   = (const float*)d_in[10];
  const float* w_fc   = (const float*)d_in[11];
  const float* b_fc   = (const float*)d_in[12];
  const float* w_fc2  = (const float*)d_in[13];
  const float* b_fc2  = (const float*)d_in[14];
  float* out = (float*)d_out;

  char* ws = (char*)d_ws;
  ushort_t* qk      = (ushort_t*)(ws + OFF_QK);
  ushort_t* h_buf   = (ushort_t*)(ws + OFF_QK);     // reuse after attention
  ushort_t* x_bf    = (ushort_t*)(ws + OFF_XBF);
  ushort_t* x1      = (ushort_t*)(ws + OFF_XBF);    // reuse after qkv GEMM
  unsigned char* bk = (unsigned char*)(ws + OFF_BUCKET);
  ushort_t* vt      = (ushort_t*)(ws + OFF_VT);
  ushort_t* y       = (ushort_t*)(ws + OFF_Y);
  ushort_t* wt_attn = (ushort_t*)(ws + OFF_WATTN);
  ushort_t* wt_proj = (ushort_t*)(ws + OFF_WPROJ);
  ushort_t* wt_fc   = (ushort_t*)(ws + OFF_WFC);
  ushort_t* wt_fc2  = (ushort_t*)(ws + OFF_WFC2);

  cvt_bf16<<<dim3(8000), 256, 0, stream>>>(x, x_bf, M_ * C_);
  WTArgs wta;
  wta.d[0] = { w_attn, wt_attn, 512, 1536 };
  wta.d[1] = { w_proj, wt_proj, 512, 512 };
  wta.d[2] = { w_fc,   wt_fc,   512, 1024 };
  wta.d[3] = { w_fc2,  wt_fc2,  1024, 512 };
  wtrans_all<<<dim3(2048), 256, 0, stream>>>(wta);
  bucket_kernel<<<dim3(500, 32), 256, 0, stream>>>(ct, bk);
  hipMemsetAsync(vt, 0, VT_BYTES, stream);   // zero the s in [500,512) pad

  // qk = (x@w_attn+b)[q,k cols]; vt = transposed v cols
  gemm_qkv<<<dim3(12, 125), 256, 0, stream>>>(x_bf, wt_attn, b_attn, qk, vt);
  attn_kernel<<<dim3(2048), 256, 0, stream>>>(qk, vt, bk, rpe, y);
  // z = x + y @ w_proj + b_proj  (f32, into d_out)
  gemm_bt<64, 2><<<dim3(8, 125), 256, 0, stream>>>(y, wt_proj, b_proj, x, nullptr, out, 512, 512);
  ln_kernel<<<dim3(16000), 256, 0, stream>>>(out, ln1w, ln1b, x1, nullptr);
  // h = gelu(x1 @ w_fc + b_fc)
  gemm_bt<128, 1><<<dim3(8, 125), 256, 0, stream>>>(x1, wt_fc, b_fc, nullptr, nullptr, h_buf, 1024, 512);
  // z2 = x1 + h @ w_fc2 + b_fc2
  gemm_bt<64, 3><<<dim3(8, 125), 256, 0, stream>>>(h_buf, wt_fc2, b_fc2, nullptr, x1, out, 512, 1024);
  ln_kernel<<<dim3(16000), 256, 0, stream>>>(out, ln2w, ln2b, nullptr, out);
}

// Round 5
// 324.750 us; speedup vs baseline: 1.2979x; 1.0824x over previous
//
#include <hip/hip_runtime.h>
#include <cstdint>
#include <cstddef>

// ---------------------------------------------------------------------------
// Block_85375359910651: RPE-attention transformer block on gfx950.
// B=32 T=500 C=512 H=8 D=64, buckets=49. bf16 MFMA pipeline (threshold 0.106).
// rpe[b,h,t,s] == rpe_table[b//4, bucket[8*(b%4)+h, t, s]]
// R5: XCD-aware GEMM block swizzle (same-m n-blocks run consecutively on one
//     XCD -> A-slice + B stay L2-resident, A fetched from HBM once);
//     bucket kernel restructured (LDS ct row, 4 t/block).
// ---------------------------------------------------------------------------

typedef unsigned short ushort_t;
typedef __bf16 bf16x8 __attribute__((ext_vector_type(8)));
typedef float floatx4 __attribute__((ext_vector_type(4)));
typedef unsigned short ushort4v __attribute__((ext_vector_type(4)));
typedef unsigned short ushort8v __attribute__((ext_vector_type(8)));

#define DEV __device__ __forceinline__

#define B_ 32
#define T_ 500
#define C_ 512
#define H_ 8
#define M_ 16000      // B*T

// ---- workspace layout (bytes), total ~94.7 MB ----
#define OFF_QK     0ULL            // 16016*1024*2 = 32,800,768  (later: h 16000*1024*2)
#define OFF_XBF    32800768ULL     // 16,384,000                 (later: x1)
#define OFF_BUCKET 49184768ULL     // 8,192,000   u8 (32,500,512) permuted
#define OFF_VT     57376768ULL     // 16,777,216  bf16 (32,8,64,512)
#define OFF_Y      74153984ULL     // 16,384,000  bf16 attn out
#define OFF_WATTN  90537984ULL     // 1,572,864   bf16 (1536,512)
#define OFF_WPROJ  92110848ULL     // 524,288     bf16 (512,512)
#define OFF_WFC    92635136ULL     // 1,048,576   bf16 (1024,512)
#define OFF_WFC2   93683712ULL     // 1,048,576   bf16 (512,1024)
#define VT_BYTES   16777216ULL

DEV ushort_t f2bf(float f) {
  union { float f; unsigned u; } v; v.f = f;
  unsigned r = v.u + 0x7fffu + ((v.u >> 16) & 1u);   // RNE
  return (ushort_t)(r >> 16);
}
DEV float bf2f(ushort_t u) {
  union { unsigned u; float f; } v; v.u = ((unsigned)u) << 16;
  return v.f;
}

DEV void gload16(const void* g, void* l) {
  __builtin_amdgcn_global_load_lds(
      (__attribute__((address_space(1))) void*)(g),
      (__attribute__((address_space(3))) void*)(l), 16, 0, 0);
}

// ---------------------------------------------------------------------------
__global__ __launch_bounds__(256) void cvt_bf16(const float* __restrict__ in,
                                                ushort_t* __restrict__ out, int n) {
  int i = (blockIdx.x * 256 + threadIdx.x) * 4;
  if (i >= n) return;
  float4 v = *(const float4*)(in + i);
  ushort4v o = { f2bf(v.x), f2bf(v.y), f2bf(v.z), f2bf(v.w) };
  *(ushort4v*)(out + i) = o;
}

// ---------------------------------------------------------------------------
// All four weight transposes in one launch. (K,N) fp32 -> (N,K) bf16.
// ---------------------------------------------------------------------------
struct WTDesc { const float* w; ushort_t* wt; int K; int N; };
struct WTArgs { WTDesc d[4]; };

__global__ __launch_bounds__(256) void wtrans_all(WTArgs a) {
  const int bid = blockIdx.x;
  int z, local;
  if (bid < 768)       { z = 0; local = bid; }
  else if (bid < 1024) { z = 1; local = bid - 768; }
  else if (bid < 1536) { z = 2; local = bid - 1024; }
  else                 { z = 3; local = bid - 1536; }
  const WTDesc dd = a.d[z];
  const int gx = dd.N >> 5;
  const int n0 = (local % gx) * 32, k0 = (local / gx) * 32;

  __shared__ float tile[32][33];
  const int c = threadIdx.x & 31, r = threadIdx.x >> 5;
#pragma unroll
  for (int rr = 0; rr < 4; ++rr)
    tile[r + rr * 8][c] = dd.w[(size_t)(k0 + r + rr * 8) * dd.N + n0 + c];
  __syncthreads();
#pragma unroll
  for (int rr = 0; rr < 4; ++rr)
    dd.wt[(size_t)(n0 + r + rr * 8) * dd.K + k0 + c] = f2bf(tile[c][r + rr * 8]);
}

// ---------------------------------------------------------------------------
// bucket ids, PERMUTED layout: row stride 512; within 64-col block, byte at
// (s&15)*4 + ((s>>4)&3) holds column s. Consumer lane l15 reads one dword at
// blk*64 + l15*4 and gets cols {0,16,32,48}+l15 in bytes 0..3.
// grid (125, 32): ct row staged in LDS, wave w handles t = bx*4 + w.
// ---------------------------------------------------------------------------
__global__ __launch_bounds__(256) void bucket_kernel(const int* __restrict__ ct,
                                                     unsigned char* __restrict__ bucket) {
  const int b = blockIdx.y;
  const int tid = threadIdx.x, w = tid >> 6, lane = tid & 63;
  __shared__ int2 ctS[500];
  for (int j = tid; j < T_; j += 256) ctS[j] = ((const int2*)ct)[(size_t)b * T_ + j];
  __syncthreads();
  const int t = blockIdx.x * 4 + w;
  const int2 a = ctS[t];
  const float ax = (float)a.x, ay = (float)a.y;
  const size_t rowbase = (size_t)(b * T_ + t) << 9;
#pragma unroll
  for (int it = 0; it < 8; ++it) {
    const int s = it * 64 + lane;
    if (s < T_) {
      const int2 c2 = ctS[s];
      const float dx = ax - (float)c2.x, dy = ay - (float)c2.y;
      const float dist = sqrtf(dx * dx + dy * dy);
      const float rel = truncf(dist / 12.0f);
      const float far = fminf(rintf(12.0f + logf(rel / 12.0f) * (12.0f / 2.0794415416798357f)), 24.0f);
      const float idx = (rel <= 12.0f) ? rel : far;
      bucket[rowbase + (s >> 6) * 64 + (s & 15) * 4 + ((s >> 4) & 3)]
          = (unsigned char)((int)idx + 24);
    }
  }
}

// ---------------------------------------------------------------------------
// qkv GEMM with fused V-transpose epilogue. A(M x 512) * Wt(1536 x 512)^T.
// Flat grid 1536 = 8 xcd * 16 mg * 12 n, XCD-swizzled: each XCD runs all 12
// n-blocks of its m-chunks consecutively (A-slice L2-resident).
// ---------------------------------------------------------------------------
__global__ __launch_bounds__(256, 2)
void gemm_qkv(const ushort_t* __restrict__ A,
              const ushort_t* __restrict__ Bt,
              const float* __restrict__ bias,
              ushort_t* __restrict__ qk,
              ushort_t* __restrict__ vt) {
  constexpr int K = 512;
  const int bid = blockIdx.x;
  const int xcd = bid & 7, k = bid >> 3;
  const int n_blk = k % 12, mg = k / 12;
  const int m_blk = mg * 8 + xcd;
  if (m_blk >= 125) return;
  const int m0 = m_blk * 128, n0 = n_blk * 128;

  __shared__ __align__(16) ushort_t As[128 * 64];
  __shared__ __align__(16) ushort_t Bs[128 * 64];
  const int tid = threadIdx.x;
  const int lane = tid & 63, w = tid >> 6;
  const int wm = w >> 1, wn = w & 1;
  const int quad = lane >> 4, l15 = lane & 15;

  floatx4 acc[4][4] = {};

  for (int k0 = 0; k0 < K; k0 += 64) {
    __syncthreads();
#pragma unroll
    for (int j = 0; j < 4; ++j) {
      const int chunk = j * 256 + tid;
      const int row = chunk >> 3, pos = chunk & 7, c = pos ^ (row & 7);
      gload16(A + (size_t)(m0 + row) * K + k0 + c * 8, (char*)As + j * 4096 + w * 1024);
      gload16(Bt + (size_t)(n0 + row) * K + k0 + c * 8, (char*)Bs + j * 4096 + w * 1024);
    }
    asm volatile("s_waitcnt vmcnt(0)" ::: "memory");
    __syncthreads();

#pragma unroll
    for (int kq = 0; kq < 2; ++kq) {
      bf16x8 af[4], bfr[4];
#pragma unroll
      for (int t = 0; t < 4; ++t) {
        const int rowa = wm * 64 + t * 16 + l15;
        const int posa = (kq * 4 + quad) ^ (rowa & 7);
        af[t] = *(const bf16x8*)((const char*)As + rowa * 128 + posa * 16);
        const int rowb = wn * 64 + t * 16 + l15;
        const int posb = (kq * 4 + quad) ^ (rowb & 7);
        bfr[t] = *(const bf16x8*)((const char*)Bs + rowb * 128 + posb * 16);
      }
#pragma unroll
      for (int tm = 0; tm < 4; ++tm)
#pragma unroll
        for (int tn = 0; tn < 4; ++tn)
          acc[tm][tn] = __builtin_amdgcn_mfma_f32_16x16x32_bf16(af[tm], bfr[tn], acc[tm][tn], 0, 0, 0);
    }
  }

  if (n0 < 1024) {   // Q,K path (uniform per block)
#pragma unroll
    for (int tn = 0; tn < 4; ++tn) {
      const int n = n0 + wn * 64 + tn * 16 + l15;
      const float bs = bias[n];
#pragma unroll
      for (int tm = 0; tm < 4; ++tm)
#pragma unroll
        for (int r = 0; r < 4; ++r) {
          const int m = m0 + wm * 64 + tm * 16 + quad * 4 + r;
          qk[(size_t)m * 1024 + n] = f2bf(acc[tm][tn][r] + bs);
        }
    }
  } else {           // V path: transpose into vt
#pragma unroll
    for (int tn = 0; tn < 4; ++tn) {
      const int n = n0 + wn * 64 + tn * 16 + l15;
      const float bs = bias[n];
      const int hh = (n >> 6) - 16, dd = n & 63;
#pragma unroll
      for (int tm = 0; tm < 4; ++tm) {
        const int mb = m0 + wm * 64 + tm * 16 + quad * 4;
        const int bb = mb / 500;
        const int ss = mb - bb * 500;
        ushort4v pk;
#pragma unroll
        for (int r = 0; r < 4; ++r) pk[r] = f2bf(acc[tm][tn][r] + bs);
        *(ushort4v*)(vt + (((size_t)(bb * 8 + hh)) * 64 + dd) * 512 + ss) = pk;
      }
    }
  }
}

// ---------------------------------------------------------------------------
// GEMM: C(M x N) = A(M x K) * Bt(N x K)^T.  128 x TN tile, BK=64, XCD swizzle.
// Flat grid 8 * 16 * (N/TN). EPI 1: bf16(gelu)  2: f32(+resf)  3: f32(+resb)
// ---------------------------------------------------------------------------
template <int TN, int EPI>
__global__ __launch_bounds__(256, TN == 64 ? 4 : 2)
void gemm_bt(const ushort_t* __restrict__ A,
             const ushort_t* __restrict__ Bt,
             const float* __restrict__ bias,
             const float* __restrict__ resf,
             const ushort_t* __restrict__ resb,
             void* __restrict__ outp,
             int N, int K) {
  constexpr int TMW = (TN == 128) ? 4 : 2;
  const int nn = N / TN;
  const int bid = blockIdx.x;
  const int xcd = bid & 7, kk = bid >> 3;
  const int n_blk = kk % nn, mg = kk / nn;
  const int m_blk = mg * 8 + xcd;
  if (m_blk >= 125) return;
  const int m0 = m_blk * 128, n0 = n_blk * TN;

  __shared__ __align__(16) ushort_t As[128 * 64];
  __shared__ __align__(16) ushort_t Bs[TN * 64];
  const int tid = threadIdx.x;
  const int lane = tid & 63, w = tid >> 6;
  const int wm = (TN == 128) ? (w >> 1) : w;
  const int wn = (TN == 128) ? (w & 1) : 0;
  const int quad = lane >> 4, l15 = lane & 15;

  floatx4 acc[TMW][4] = {};

  for (int k0 = 0; k0 < K; k0 += 64) {
    __syncthreads();
#pragma unroll
    for (int j = 0; j < 4; ++j) {
      const int chunk = j * 256 + tid;
      const int row = chunk >> 3, pos = chunk & 7, c = pos ^ (row & 7);
      gload16(A + (size_t)(m0 + row) * K + k0 + c * 8, (char*)As + j * 4096 + w * 1024);
    }
#pragma unroll
    for (int j = 0; j < TN / 32; ++j) {
      const int chunk = j * 256 + tid;
      const int row = chunk >> 3, pos = chunk & 7, c = pos ^ (row & 7);
      gload16(Bt + (size_t)(n0 + row) * K + k0 + c * 8, (char*)Bs + j * 4096 + w * 1024);
    }
    asm volatile("s_waitcnt vmcnt(0)" ::: "memory");
    __syncthreads();

#pragma unroll
    for (int kq = 0; kq < 2; ++kq) {
      bf16x8 af[TMW], bfr[4];
#pragma unroll
      for (int t = 0; t < TMW; ++t) {
        const int row = wm * (TMW * 16) + t * 16 + l15;
        const int pos = (kq * 4 + quad) ^ (row & 7);
        af[t] = *(const bf16x8*)((const char*)As + row * 128 + pos * 16);
      }
#pragma unroll
      for (int t = 0; t < 4; ++t) {
        const int row = wn * 64 + t * 16 + l15;
        const int pos = (kq * 4 + quad) ^ (row & 7);
        bfr[t] = *(const bf16x8*)((const char*)Bs + row * 128 + pos * 16);
      }
#pragma unroll
      for (int tm = 0; tm < TMW; ++tm)
#pragma unroll
        for (int tn = 0; tn < 4; ++tn)
          acc[tm][tn] = __builtin_amdgcn_mfma_f32_16x16x32_bf16(af[tm], bfr[tn], acc[tm][tn], 0, 0, 0);
    }
  }

#pragma unroll
  for (int tn = 0; tn < 4; ++tn) {
    const int n = n0 + wn * 64 + tn * 16 + l15;
    const float bs = bias[n];
#pragma unroll
    for (int tm = 0; tm < TMW; ++tm) {
#pragma unroll
      for (int r = 0; r < 4; ++r) {
        const int m = m0 + wm * (TMW * 16) + tm * 16 + quad * 4 + r;
        const float v = acc[tm][tn][r] + bs;
        if (EPI == 1) {
          const float gv = 0.5f * v * (1.0f + erff(v * 0.70710678118654752f));
          ((ushort_t*)outp)[(size_t)m * N + n] = f2bf(gv);
        } else if (EPI == 2) {
          ((float*)outp)[(size_t)m * N + n] = v + resf[(size_t)m * N + n];
        } else {
          ((float*)outp)[(size_t)m * N + n] = v + bf2f(resb[(size_t)m * N + n]);
        }
      }
    }
  }
}

// ---------------------------------------------------------------------------
// fused flash attention with RPE bias. No-max softmax, deferred row-sum.
// LDS 25.5 KB. Bucket read directly from global (pre-permuted dwords).
// grid 2048 flat (XCD-swizzled), 256 threads (4 waves x 16 q-rows).
// ---------------------------------------------------------------------------
__global__ __launch_bounds__(256, 5) void attn_kernel(const ushort_t* __restrict__ qk,
                                                      const ushort_t* __restrict__ vt,
                                                      const unsigned char* __restrict__ bucket,
                                                      const float* __restrict__ rpe,
                                                      ushort_t* __restrict__ y) {
  const int bid = blockIdx.x;
  const int xcd = bid & 7, sl = bid >> 3;
  const int qt = sl & 7;
  const int pair = xcd * 32 + (sl >> 3);
  const int h = pair >> 5, b = pair & 31;
  const int g = b >> 2;
  const int bpp = 8 * (b & 3) + h;

  __shared__ __align__(16) ushort_t Qs[64 * 64];    // reused as P after qf load
  __shared__ __align__(16) ushort_t Ks[64 * 64];
  __shared__ __align__(16) ushort_t VTs[64 * 64];
  __shared__ float tbl2[224];                       // 4 quad replicas, stride 52

  const int tid = threadIdx.x;
  const int lane = tid & 63, w = tid >> 6;
  const int quad = lane >> 4, l15 = lane & 15;
  const int t0 = qt * 64;

#pragma unroll
  for (int j = 0; j < 2; ++j) {
    const int chunk = j * 256 + tid;
    const int row = chunk >> 3, pos = chunk & 7, c = pos ^ (row & 7);
    gload16(qk + (size_t)(b * T_ + t0 + row) * 1024 + h * 64 + c * 8,
            (char*)Qs + j * 4096 + w * 1024);
  }
  if (tid < 224) {
    const int q = tid / 52, i = tid - q * 52;
    tbl2[tid] = (q < 4 && i < 49) ? rpe[g * 49 + i] * 1.44269504f : 0.0f;
  }
  asm volatile("s_waitcnt vmcnt(0)" ::: "memory");
  __syncthreads();

  bf16x8 qf[2];
#pragma unroll
  for (int kq = 0; kq < 2; ++kq) {
    const int row = w * 16 + l15;
    const int pos = (kq * 4 + quad) ^ (row & 7);
    qf[kq] = *(const bf16x8*)((const char*)Qs + row * 128 + pos * 16);
  }

  floatx4 o[4] = {};
  float lsum[4] = {0.0f, 0.0f, 0.0f, 0.0f};
  char* pw = (char*)Qs + w * 2048;   // wave-private P region (16 rows x 128 B)

  // bucket row base addresses for this lane's 4 q-rows (clamped)
  const unsigned char* bkbase[4];
#pragma unroll
  for (int r = 0; r < 4; ++r) {
    const int tr = t0 + w * 16 + quad * 4 + r;
    const int trc = (tr < T_) ? tr : (T_ - 1);
    bkbase[r] = bucket + ((size_t)(bpp * T_ + trc) << 9) + (l15 << 2);
  }

  for (int st = 0; st < 8; ++st) {
    const int s0 = st * 64;
    __syncthreads();   // protect Ks/VTs from previous iteration's readers
#pragma unroll
    for (int j = 0; j < 2; ++j) {
      const int chunk = j * 256 + tid;
      const int row = chunk >> 3, pos = chunk & 7, c = pos ^ (row & 7);
      gload16(qk + (size_t)(b * T_ + s0 + row) * 1024 + 512 + h * 64 + c * 8,
              (char*)Ks + j * 4096 + w * 1024);
      gload16(vt + ((size_t)(b * 8 + h) * 64 + row) * 512 + s0 + c * 8,
              (char*)VTs + j * 4096 + w * 1024);
    }
    // bucket dwords: 4 tn-values per q-row packed per dword (permuted layout)
    unsigned bw[4];
#pragma unroll
    for (int r = 0; r < 4; ++r) bw[r] = *(const unsigned*)(bkbase[r] + s0);
    asm volatile("s_waitcnt vmcnt(0)" ::: "memory");
    __syncthreads();

    // QK^T
    floatx4 sc[4];
#pragma unroll
    for (int tn = 0; tn < 4; ++tn) {
      floatx4 z = {0.0f, 0.0f, 0.0f, 0.0f};
#pragma unroll
      for (int kq = 0; kq < 2; ++kq) {
        const int row = tn * 16 + l15;
        const int pos = (kq * 4 + quad) ^ (row & 7);
        const bf16x8 kf = *(const bf16x8*)((const char*)Ks + row * 128 + pos * 16);
        z = __builtin_amdgcn_mfma_f32_16x16x32_bf16(qf[kq], kf, z, 0, 0, 0);
      }
      sc[tn] = z;
    }

    // P = exp2(score*0.125*log2e + tbl2[bucket]); trunc-store bf16 into pw
#pragma unroll
    for (int r = 0; r < 4; ++r) {
      const int prow = quad * 4 + r;
#pragma unroll
      for (int tn = 0; tn < 4; ++tn) {
        const int scol = s0 + tn * 16 + l15;
        const int idx = (bw[r] >> (tn * 8)) & 63;
        const float val = fmaf(sc[tn][r], 0.18033688f, tbl2[quad * 52 + idx]);
        const float p = (scol < T_) ? exp2f(val) : 0.0f;
        lsum[r] += p;
        const int chunk = (tn * 2 + (l15 >> 3)) ^ (prow & 7);
        *(ushort_t*)(pw + prow * 128 + chunk * 16 + (l15 & 7) * 2) =
            (ushort_t)(__builtin_bit_cast(unsigned, p) >> 16);   // trunc bf16
      }
    }
    asm volatile("" ::: "memory");   // order P stores before same-wave frag reads

    // PV
#pragma unroll
    for (int ks = 0; ks < 2; ++ks) {
      const int ppos = (ks * 4 + quad) ^ (l15 & 7);
      const bf16x8 pf = *(const bf16x8*)(pw + l15 * 128 + ppos * 16);
#pragma unroll
      for (int nd = 0; nd < 4; ++nd) {
        const int row = nd * 16 + l15;
        const int pos = (ks * 4 + quad) ^ (row & 7);
        const bf16x8 vf = *(const bf16x8*)((const char*)VTs + row * 128 + pos * 16);
        o[nd] = __builtin_amdgcn_mfma_f32_16x16x32_bf16(pf, vf, o[nd], 0, 0, 0);
      }
    }
  }

  // deferred row-sum reduce + write
#pragma unroll
  for (int r = 0; r < 4; ++r) {
    float s = lsum[r];
    s += __shfl_xor(s, 1);
    s += __shfl_xor(s, 2);
    s += __shfl_xor(s, 4);
    s += __shfl_xor(s, 8);
    const int t = t0 + w * 16 + quad * 4 + r;
    if (t < T_) {
      const float inv = 1.0f / s;
#pragma unroll
      for (int nd = 0; nd < 4; ++nd)
        y[((size_t)b * T_ + t) * 512 + h * 64 + nd * 16 + l15] = f2bf(o[nd][r] * inv);
    }
  }
}

// ---------------------------------------------------------------------------
__global__ __launch_bounds__(256) void ln_kernel(const float* z,
                                                 const float* __restrict__ gw,
                                                 const float* __restrict__ gb,
                                                 ushort_t* out_bf, float* out_f) {
  const int row = blockIdx.x;
  const int tid = threadIdx.x, lane = tid & 63, w = tid >> 6;
  const float* zr = z + (size_t)row * 512;
  const float2 v = *(const float2*)(zr + tid * 2);
  float s = v.x + v.y;
#pragma unroll
  for (int m = 1; m < 64; m <<= 1) s += __shfl_xor(s, m);
  __shared__ float red[8];
  if (lane == 0) red[w] = s;
  __syncthreads();
  const float mean = (red[0] + red[1] + red[2] + red[3]) * (1.0f / 512.0f);
  const float d0 = v.x - mean, d1 = v.y - mean;
  float q = d0 * d0 + d1 * d1;
#pragma unroll
  for (int m = 1; m < 64; m <<= 1) q += __shfl_xor(q, m);
  if (lane == 0) red[4 + w] = q;
  __syncthreads();
  const float var = (red[4] + red[5] + red[6] + red[7]) * (1.0f / 512.0f);
  const float rstd = rsqrtf(var + 1e-5f);
  const int c0 = tid * 2;
  const float o0 = d0 * rstd * gw[c0] + gb[c0];
  const float o1 = d1 * rstd * gw[c0 + 1] + gb[c0 + 1];
  if (out_bf) {
    out_bf[(size_t)row * 512 + c0] = f2bf(o0);
    out_bf[(size_t)row * 512 + c0 + 1] = f2bf(o1);
  }
  if (out_f) {
    float2 ov; ov.x = o0; ov.y = o1;
    *(float2*)(out_f + (size_t)row * 512 + c0) = ov;
  }
}

// ---------------------------------------------------------------------------
extern "C" void kernel_launch(void* const* d_in, const int* in_sizes, int n_in,
                              void* d_out, int out_size, void* d_ws, size_t ws_size,
                              hipStream_t stream) {
  (void)in_sizes; (void)n_in; (void)out_size; (void)ws_size;
  const float* x      = (const float*)d_in[0];
  const int*   ct     = (const int*)d_in[1];
  const float* w_attn = (const float*)d_in[2];
  const float* b_attn = (const float*)d_in[3];
  const float* w_proj = (const float*)d_in[4];
  const float* b_proj = (const float*)d_in[5];
  const float* rpe    = (const float*)d_in[6];
  const float* ln1w   = (const float*)d_in[7];
  const float* ln1b   = (const float*)d_in[8];
  const float* ln2w   = (const float*)d_in[9];
  const float* ln2b   = (const float*)d_in[10];
  const float* w_fc   = (const float*)d_in[11];
  const float* b_fc   = (const float*)d_in[12];
  const float* w_fc2  = (const float*)d_in[13];
  const float* b_fc2  = (const float*)d_in[14];
  float* out = (float*)d_out;

  char* ws = (char*)d_ws;
  ushort_t* qk      = (ushort_t*)(ws + OFF_QK);
  ushort_t* h_buf   = (ushort_t*)(ws + OFF_QK);     // reuse after attention
  ushort_t* x_bf    = (ushort_t*)(ws + OFF_XBF);
  ushort_t* x1      = (ushort_t*)(ws + OFF_XBF);    // reuse after qkv GEMM
  unsigned char* bk = (unsigned char*)(ws + OFF_BUCKET);
  ushort_t* vt      = (ushort_t*)(ws + OFF_VT);
  ushort_t* y       = (ushort_t*)(ws + OFF_Y);
  ushort_t* wt_attn = (ushort_t*)(ws + OFF_WATTN);
  ushort_t* wt_proj = (ushort_t*)(ws + OFF_WPROJ);
  ushort_t* wt_fc   = (ushort_t*)(ws + OFF_WFC);
  ushort_t* wt_fc2  = (ushort_t*)(ws + OFF_WFC2);

  cvt_bf16<<<dim3(8000), 256, 0, stream>>>(x, x_bf, M_ * C_);
  WTArgs wta;
  wta.d[0] = { w_attn, wt_attn, 512, 1536 };
  wta.d[1] = { w_proj, wt_proj, 512, 512 };
  wta.d[2] = { w_fc,   wt_fc,   512, 1024 };
  wta.d[3] = { w_fc2,  wt_fc2,  1024, 512 };
  wtrans_all<<<dim3(2048), 256, 0, stream>>>(wta);
  bucket_kernel<<<dim3(125, 32), 256, 0, stream>>>(ct, bk);
  hipMemsetAsync(vt, 0, VT_BYTES, stream);   // zero the s in [500,512) pad

  // qk = (x@w_attn+b)[q,k cols]; vt = transposed v cols   (grid 8*16*12)
  gemm_qkv<<<dim3(1536), 256, 0, stream>>>(x_bf, wt_attn, b_attn, qk, vt);
  attn_kernel<<<dim3(2048), 256, 0, stream>>>(qk, vt, bk, rpe, y);
  // z = x + y @ w_proj + b_proj  (f32, into d_out)   (grid 8*16*8)
  gemm_bt<64, 2><<<dim3(1024), 256, 0, stream>>>(y, wt_proj, b_proj, x, nullptr, out, 512, 512);
  ln_kernel<<<dim3(16000), 256, 0, stream>>>(out, ln1w, ln1b, x1, nullptr);
  // h = gelu(x1 @ w_fc + b_fc)   (grid 8*16*8)
  gemm_bt<128, 1><<<dim3(1024), 256, 0, stream>>>(x1, wt_fc, b_fc, nullptr, nullptr, h_buf, 1024, 512);
  // z2 = x1 + h @ w_fc2 + b_fc2   (grid 8*16*8)
  gemm_bt<64, 3><<<dim3(1024), 256, 0, stream>>>(h_buf, wt_fc2, b_fc2, nullptr, x1, out, 512, 1024);
  ln_kernel<<<dim3(16000), 256, 0, stream>>>(out, ln2w, ln2b, nullptr, out);
}